// Round 2
// baseline (1149.630 us; speedup 1.0000x reference)
//
#include <hip/hip_runtime.h>
#include <math.h>

#define NTOK 1024
#define DIMM 512
#define NHEAD 8
#define DHEAD 64
#define JTOT 1026      // NTOK + 2 null kv
#define JPAD 1088      // 17*64, padded row for unguarded loads

// ---------------- wave reductions (64 lanes) ----------------
__device__ __forceinline__ float wave_sum64(float x) {
    x += __int_as_float(__builtin_amdgcn_ds_swizzle(__float_as_int(x), 0x041F)); // ^1
    x += __int_as_float(__builtin_amdgcn_ds_swizzle(__float_as_int(x), 0x081F)); // ^2
    x += __int_as_float(__builtin_amdgcn_ds_swizzle(__float_as_int(x), 0x101F)); // ^4
    x += __int_as_float(__builtin_amdgcn_ds_swizzle(__float_as_int(x), 0x201F)); // ^8
    x += __int_as_float(__builtin_amdgcn_ds_swizzle(__float_as_int(x), 0x401F)); // ^16
    x += __shfl_xor(x, 32);
    return x;
}
__device__ __forceinline__ float wave_max64(float x) {
    x = fmaxf(x, __int_as_float(__builtin_amdgcn_ds_swizzle(__float_as_int(x), 0x041F)));
    x = fmaxf(x, __int_as_float(__builtin_amdgcn_ds_swizzle(__float_as_int(x), 0x081F)));
    x = fmaxf(x, __int_as_float(__builtin_amdgcn_ds_swizzle(__float_as_int(x), 0x101F)));
    x = fmaxf(x, __int_as_float(__builtin_amdgcn_ds_swizzle(__float_as_int(x), 0x201F)));
    x = fmaxf(x, __int_as_float(__builtin_amdgcn_ds_swizzle(__float_as_int(x), 0x401F)));
    x = fmaxf(x, __shfl_xor(x, 32));
    return x;
}

// ---------------- LayerNorm ----------------
__global__ __launch_bounds__(128) void ln_kernel(const float* __restrict__ x,
                                                 const float* __restrict__ g,
                                                 const float* __restrict__ bb,
                                                 float* __restrict__ xn) {
    int row = blockIdx.x, tid = threadIdx.x;
    float4 v = ((const float4*)(x + row * DIMM))[tid];
    float s  = v.x + v.y + v.z + v.w;
    float ss = fmaf(v.x, v.x, fmaf(v.y, v.y, fmaf(v.z, v.z, v.w * v.w)));
#pragma unroll
    for (int off = 32; off; off >>= 1) {
        s  += __shfl_down(s, off);
        ss += __shfl_down(ss, off);
    }
    __shared__ float sm[4];
    if ((tid & 63) == 0) { sm[(tid >> 6) * 2] = s; sm[(tid >> 6) * 2 + 1] = ss; }
    __syncthreads();
    s = sm[0] + sm[2]; ss = sm[1] + sm[3];
    float mu   = s * (1.f / DIMM);
    float var  = ss * (1.f / DIMM) - mu * mu;
    float rstd = 1.f / sqrtf(var + 1e-5f);
    float4 gv = ((const float4*)g)[tid];
    float4 bv = ((const float4*)bb)[tid];
    float4 o;
    o.x = (v.x - mu) * rstd * gv.x + bv.x;
    o.y = (v.y - mu) * rstd * gv.y + bv.y;
    o.z = (v.z - mu) * rstd * gv.z + bv.z;
    o.w = (v.w - mu) * rstd * gv.w + bv.w;
    ((float4*)(xn + row * DIMM))[tid] = o;
}

// ---------------- null kv fill ----------------
__global__ __launch_bounds__(256) void nullkv_kernel(const float* __restrict__ nkv,
                                                     float* __restrict__ kT,
                                                     float* __restrict__ vv) {
    int tid = blockIdx.x * 256 + threadIdx.x;  // 1024 total
    if (tid >= NHEAD * 2 * DHEAD) return;
    int d = tid & 63, p = (tid >> 6) & 1, h = tid >> 7;
    float kval = nkv[((0 * NHEAD + h) * 2 + p) * DHEAD + d];
    float vval = nkv[((1 * NHEAD + h) * 2 + p) * DHEAD + d];
    kT[(h * DHEAD + d) * JPAD + p] = kval;
    vv[(h * JTOT + p) * DHEAD + d] = vval;
}

// ---------------- QKV GEMM: xn[1024][512] @ w_qkv[512][1536] ----------------
__global__ __launch_bounds__(256) void qkv_gemm(const float* __restrict__ A,
                                                const float* __restrict__ B,
                                                float* __restrict__ qo,
                                                float* __restrict__ kT,
                                                float* __restrict__ vo) {
    const int K = 512, Nn = 1536;
    __shared__ float As[16][64];
    __shared__ float Bs[16][64];
    int tid = threadIdx.x;
    int m0 = blockIdx.x * 64, n0 = blockIdx.y * 64;
    int ty = tid >> 4, tx = tid & 15;
    int lam = tid >> 2, lak = (tid & 3) << 2;
    int lbk = tid >> 4, lbn = (tid & 15) << 2;
    float acc[4][4] = {};
    for (int k0 = 0; k0 < K; k0 += 16) {
        float4 av = *(const float4*)(A + (m0 + lam) * K + k0 + lak);
        float4 bv = *(const float4*)(B + (size_t)(k0 + lbk) * Nn + n0 + lbn);
        As[lak + 0][lam] = av.x; As[lak + 1][lam] = av.y;
        As[lak + 2][lam] = av.z; As[lak + 3][lam] = av.w;
        *(float4*)&Bs[lbk][lbn] = bv;
        __syncthreads();
#pragma unroll
        for (int kk = 0; kk < 16; ++kk) {
            float a4[4], b4[4];
#pragma unroll
            for (int u = 0; u < 4; ++u) a4[u] = As[kk][ty * 4 + u];
#pragma unroll
            for (int u = 0; u < 4; ++u) b4[u] = Bs[kk][tx * 4 + u];
#pragma unroll
            for (int ii = 0; ii < 4; ++ii)
#pragma unroll
                for (int jj = 0; jj < 4; ++jj)
                    acc[ii][jj] = fmaf(a4[ii], b4[jj], acc[ii][jj]);
        }
        __syncthreads();
    }
#pragma unroll
    for (int ii = 0; ii < 4; ++ii) {
        int m = m0 + ty * 4 + ii;
#pragma unroll
        for (int jj = 0; jj < 4; ++jj) {
            int c = n0 + tx * 4 + jj;
            float val = acc[ii][jj];
            if (c < 512) {
                int h = c >> 6, d = c & 63;
                qo[((h << 10) + m) * 64 + d] = val * 0.125f;
            } else if (c < 1024) {
                int c2 = c - 512, h = c2 >> 6, d = c2 & 63;
                kT[(h * 64 + d) * JPAD + 2 + m] = val;
            } else {
                int c2 = c - 1024, h = c2 >> 6, d = c2 & 63;
                vo[(h * JTOT + 2 + m) * DHEAD + d] = val;
            }
        }
    }
}

// ---------------- fused sim + coordinate descent + PV ----------------
// One wave per (head,row). Fixed-shift trick: with M = max(s10), the CD
// iteration in aM = a10 + M form is  aM = ln8 - log(sum(exp(zm))),
// zm = s10m + min(0, s10m + aM), s10m = s10 - M <= 0.
// Provably no overflow/underflow: sum in [exp(-4.85), 1026].
template<int NTv>
__device__ __forceinline__ void cd_body(const float* __restrict__ ktb,
                                        const float* __restrict__ vb,
                                        const float* qsw, float* psw,
                                        int nvalid, int lane,
                                        float* __restrict__ outp) {
    const int tmax = (nvalid + 63) >> 6;
    float s10m[NTv];
    float M = -INFINITY;
#pragma unroll
    for (int t = 0; t < NTv; ++t) {
        float a0 = 0.f, a1 = 0.f, a2 = 0.f, a3 = 0.f;
        if (t < tmax) {
            const float* p0 = ktb + (t << 6);
#pragma unroll
            for (int d = 0; d < 64; d += 4) {
                float4 qv = *(const float4*)(qsw + d);
                a0 = fmaf(qv.x, p0[(size_t)(d + 0) * JPAD], a0);
                a1 = fmaf(qv.y, p0[(size_t)(d + 1) * JPAD], a1);
                a2 = fmaf(qv.z, p0[(size_t)(d + 2) * JPAD], a2);
                a3 = fmaf(qv.w, p0[(size_t)(d + 3) * JPAD], a3);
            }
        }
        int j = lane + (t << 6);
        float sv = ((a0 + a1) + (a2 + a3)) * 10.f;
        s10m[t] = (j < nvalid) ? sv : -INFINITY;
        M = fmaxf(M, s10m[t]);
    }
    M = wave_max64(M);
#pragma unroll
    for (int t = 0; t < NTv; ++t) s10m[t] -= M;   // -inf stays -inf

    const float LOGK = 2.0794415416798357f;  // ln 8
    // iteration 1 analytic: sb == 0 on mask -> lse = log(nvalid)
    float aM = LOGK - __logf((float)nvalid) + M;
#pragma unroll 1
    for (int it = 1; it < 50; ++it) {
        float sum = 0.f;
#pragma unroll
        for (int t = 0; t < NTv; ++t) {
            float tmp = s10m[t] + aM;
            float zm = s10m[t] + fminf(0.f, tmp);
            sum += __expf(zm);
        }
        sum = wave_sum64(sum);
        float aMn = LOGK - __logf(sum);
        bool conv = (__float_as_int(aMn) == __float_as_int(aM));
        aM = aMn;
        if (conv) break;   // bitwise fixed point: rest of iterations are identity
    }

    // final scores -> LDS (masked slots produce exp(-inf)=0)
#pragma unroll
    for (int t = 0; t < NTv; ++t) {
        float tmp = s10m[t] + aM;          // = s10 + a10
        float p = __expf(tmp + fminf(0.f, tmp));
        psw[lane + (t << 6)] = p;
    }

    // PV: lane = d, loop j
    float b0 = 0.f, b1 = 0.f, b2 = 0.f, b3 = 0.f;
    int j = 0;
    for (; j + 4 <= nvalid; j += 4) {
        float4 p4 = *(const float4*)(psw + j);
        b0 = fmaf(p4.x, vb[(size_t)(j + 0) * 64], b0);
        b1 = fmaf(p4.y, vb[(size_t)(j + 1) * 64], b1);
        b2 = fmaf(p4.z, vb[(size_t)(j + 2) * 64], b2);
        b3 = fmaf(p4.w, vb[(size_t)(j + 3) * 64], b3);
    }
    for (; j < nvalid; ++j) b0 = fmaf(psw[j], vb[(size_t)j * 64], b0);
    *outp = (b0 + b1) + (b2 + b3);
}

__global__ __launch_bounds__(256) void cd_kernel(const float* __restrict__ q,
                                                 const float* __restrict__ kT,
                                                 const float* __restrict__ vv,
                                                 float* __restrict__ ao) {
    __shared__ float qs[4][64];
    __shared__ float ps[4][JPAD];
    int wave = threadIdx.x >> 6, lane = threadIdx.x & 63;
    int idx = (blockIdx.x << 2) + wave;
    int i = 1023 - (idx >> 3);    // longest rows scheduled first
    int h = idx & 7;
    int nvalid = i + 3;           // 2 null kv + causal i+1

    qs[wave][lane] = q[(((h << 10) + i) << 6) + lane];  // wave-private, no barrier

    const float* ktb = kT + (size_t)(h << 6) * JPAD + lane;
    const float* vb  = vv + (size_t)h * JTOT * DHEAD + lane;
    float* outp = ao + (i << 9) + (h << 6) + lane;

    int tmax = (nvalid + 63) >> 6;
    if (tmax <= 5)       cd_body<5>(ktb, vb, qs[wave], ps[wave], nvalid, lane, outp);
    else if (tmax <= 9)  cd_body<9>(ktb, vb, qs[wave], ps[wave], nvalid, lane, outp);
    else if (tmax <= 13) cd_body<13>(ktb, vb, qs[wave], ps[wave], nvalid, lane, outp);
    else                 cd_body<17>(ktb, vb, qs[wave], ps[wave], nvalid, lane, outp);
}

// ---------------- out GEMM: ao[1024][512] @ w_out[512][512] -> d_out ----------------
__global__ __launch_bounds__(256) void out_gemm(const float* __restrict__ A,
                                                const float* __restrict__ B,
                                                float* __restrict__ C) {
    const int K = 512, Nn = 512;
    __shared__ float As[16][64];
    __shared__ float Bs[16][64];
    int tid = threadIdx.x;
    int m0 = blockIdx.x * 64, n0 = blockIdx.y * 64;
    int ty = tid >> 4, tx = tid & 15;
    int lam = tid >> 2, lak = (tid & 3) << 2;
    int lbk = tid >> 4, lbn = (tid & 15) << 2;
    float acc[4][4] = {};
    for (int k0 = 0; k0 < K; k0 += 16) {
        float4 av = *(const float4*)(A + (m0 + lam) * K + k0 + lak);
        float4 bv = *(const float4*)(B + (size_t)(k0 + lbk) * Nn + n0 + lbn);
        As[lak + 0][lam] = av.x; As[lak + 1][lam] = av.y;
        As[lak + 2][lam] = av.z; As[lak + 3][lam] = av.w;
        *(float4*)&Bs[lbk][lbn] = bv;
        __syncthreads();
#pragma unroll
        for (int kk = 0; kk < 16; ++kk) {
            float a4[4], b4[4];
#pragma unroll
            for (int u = 0; u < 4; ++u) a4[u] = As[kk][ty * 4 + u];
#pragma unroll
            for (int u = 0; u < 4; ++u) b4[u] = Bs[kk][tx * 4 + u];
#pragma unroll
            for (int ii = 0; ii < 4; ++ii)
#pragma unroll
                for (int jj = 0; jj < 4; ++jj)
                    acc[ii][jj] = fmaf(a4[ii], b4[jj], acc[ii][jj]);
        }
        __syncthreads();
    }
#pragma unroll
    for (int ii = 0; ii < 4; ++ii) {
        int m = m0 + ty * 4 + ii;
#pragma unroll
        for (int jj = 0; jj < 4; ++jj) {
            int c = n0 + tx * 4 + jj;
            C[m * Nn + c] = acc[ii][jj];
        }
    }
}

extern "C" void kernel_launch(void* const* d_in, const int* in_sizes, int n_in,
                              void* d_out, int out_size, void* d_ws, size_t ws_size,
                              hipStream_t stream) {
    const float* x      = (const float*)d_in[0];
    const float* w_qkv  = (const float*)d_in[1];
    const float* w_out  = (const float*)d_in[2];
    const float* nullkv = (const float*)d_in[3];
    const float* ln_g   = (const float*)d_in[4];
    const float* ln_b   = (const float*)d_in[5];
    float* ws = (float*)d_ws;

    float* xn = ws;                                  // 1024*512
    float* q  = xn + 1024 * 512;                     // 8*1024*64
    float* kT = q + 8 * 1024 * 64;                   // 8*64*JPAD
    float* vv = kT + 8 * 64 * JPAD;                  // 8*JTOT*64
    float* ao = vv + 8 * JTOT * 64;                  // 1024*512
    float* out = (float*)d_out;

    hipLaunchKernelGGL(ln_kernel, dim3(1024), dim3(128), 0, stream, x, ln_g, ln_b, xn);
    hipLaunchKernelGGL(nullkv_kernel, dim3(4), dim3(256), 0, stream, nullkv, kT, vv);
    hipLaunchKernelGGL(qkv_gemm, dim3(16, 24), dim3(256), 0, stream, xn, w_qkv, q, kT, vv);
    hipLaunchKernelGGL(cd_kernel, dim3(2048), dim3(256), 0, stream, q, kT, vv, ao);
    hipLaunchKernelGGL(out_gemm, dim3(16, 8), dim3(256), 0, stream, ao, w_out, out);
}

// Round 3
// 265.086 us; speedup vs baseline: 4.3368x; 4.3368x over previous
//
#include <hip/hip_runtime.h>
#include <math.h>

#define NTOK 1024
#define DIMM 512
#define NHEAD 8
#define DHEAD 64
#define JTOT 1026      // NTOK + 2 null kv
#define JPAD 1088      // 17*64, padded row for unguarded loads
#define NT 17

// ---------------- wave reductions (64 lanes) ----------------
__device__ __forceinline__ float wave_sum64(float x) {
    x += __int_as_float(__builtin_amdgcn_ds_swizzle(__float_as_int(x), 0x041F)); // ^1
    x += __int_as_float(__builtin_amdgcn_ds_swizzle(__float_as_int(x), 0x081F)); // ^2
    x += __int_as_float(__builtin_amdgcn_ds_swizzle(__float_as_int(x), 0x101F)); // ^4
    x += __int_as_float(__builtin_amdgcn_ds_swizzle(__float_as_int(x), 0x201F)); // ^8
    x += __int_as_float(__builtin_amdgcn_ds_swizzle(__float_as_int(x), 0x401F)); // ^16
    x += __shfl_xor(x, 32);
    return x;
}
__device__ __forceinline__ float wave_max64(float x) {
    x = fmaxf(x, __int_as_float(__builtin_amdgcn_ds_swizzle(__float_as_int(x), 0x041F)));
    x = fmaxf(x, __int_as_float(__builtin_amdgcn_ds_swizzle(__float_as_int(x), 0x081F)));
    x = fmaxf(x, __int_as_float(__builtin_amdgcn_ds_swizzle(__float_as_int(x), 0x101F)));
    x = fmaxf(x, __int_as_float(__builtin_amdgcn_ds_swizzle(__float_as_int(x), 0x201F)));
    x = fmaxf(x, __int_as_float(__builtin_amdgcn_ds_swizzle(__float_as_int(x), 0x401F)));
    x = fmaxf(x, __shfl_xor(x, 32));
    return x;
}

// ---------------- LayerNorm ----------------
__global__ __launch_bounds__(128) void ln_kernel(const float* __restrict__ x,
                                                 const float* __restrict__ g,
                                                 const float* __restrict__ bb,
                                                 float* __restrict__ xn) {
    int row = blockIdx.x, tid = threadIdx.x;
    float4 v = ((const float4*)(x + row * DIMM))[tid];
    float s  = v.x + v.y + v.z + v.w;
    float ss = fmaf(v.x, v.x, fmaf(v.y, v.y, fmaf(v.z, v.z, v.w * v.w)));
#pragma unroll
    for (int off = 32; off; off >>= 1) {
        s  += __shfl_down(s, off);
        ss += __shfl_down(ss, off);
    }
    __shared__ float sm[4];
    if ((tid & 63) == 0) { sm[(tid >> 6) * 2] = s; sm[(tid >> 6) * 2 + 1] = ss; }
    __syncthreads();
    s = sm[0] + sm[2]; ss = sm[1] + sm[3];
    float mu   = s * (1.f / DIMM);
    float var  = ss * (1.f / DIMM) - mu * mu;
    float rstd = 1.f / sqrtf(var + 1e-5f);
    float4 gv = ((const float4*)g)[tid];
    float4 bv = ((const float4*)bb)[tid];
    float4 o;
    o.x = (v.x - mu) * rstd * gv.x + bv.x;
    o.y = (v.y - mu) * rstd * gv.y + bv.y;
    o.z = (v.z - mu) * rstd * gv.z + bv.z;
    o.w = (v.w - mu) * rstd * gv.w + bv.w;
    ((float4*)(xn + row * DIMM))[tid] = o;
}

// ---------------- null kv fill ----------------
__global__ __launch_bounds__(256) void nullkv_kernel(const float* __restrict__ nkv,
                                                     float* __restrict__ kT,
                                                     float* __restrict__ vv) {
    int tid = blockIdx.x * 256 + threadIdx.x;  // 1024 total
    if (tid >= NHEAD * 2 * DHEAD) return;
    int d = tid & 63, p = (tid >> 6) & 1, h = tid >> 7;
    float kval = nkv[((0 * NHEAD + h) * 2 + p) * DHEAD + d];
    float vval = nkv[((1 * NHEAD + h) * 2 + p) * DHEAD + d];
    kT[(h * DHEAD + d) * JPAD + p] = kval;
    vv[(h * JTOT + p) * DHEAD + d] = vval;
}

// ---------------- QKV GEMM: xn[1024][512] @ w_qkv[512][1536] ----------------
__global__ __launch_bounds__(256) void qkv_gemm(const float* __restrict__ A,
                                                const float* __restrict__ B,
                                                float* __restrict__ qo,
                                                float* __restrict__ kT,
                                                float* __restrict__ vo) {
    const int K = 512, Nn = 1536;
    __shared__ float As[16][64];
    __shared__ float Bs[16][64];
    int tid = threadIdx.x;
    int m0 = blockIdx.x * 64, n0 = blockIdx.y * 64;
    int ty = tid >> 4, tx = tid & 15;
    int lam = tid >> 2, lak = (tid & 3) << 2;
    int lbk = tid >> 4, lbn = (tid & 15) << 2;
    float acc[4][4] = {};
    for (int k0 = 0; k0 < K; k0 += 16) {
        float4 av = *(const float4*)(A + (m0 + lam) * K + k0 + lak);
        float4 bv = *(const float4*)(B + (size_t)(k0 + lbk) * Nn + n0 + lbn);
        As[lak + 0][lam] = av.x; As[lak + 1][lam] = av.y;
        As[lak + 2][lam] = av.z; As[lak + 3][lam] = av.w;
        *(float4*)&Bs[lbk][lbn] = bv;
        __syncthreads();
#pragma unroll
        for (int kk = 0; kk < 16; ++kk) {
            float a4[4], b4[4];
#pragma unroll
            for (int u = 0; u < 4; ++u) a4[u] = As[kk][ty * 4 + u];
#pragma unroll
            for (int u = 0; u < 4; ++u) b4[u] = Bs[kk][tx * 4 + u];
#pragma unroll
            for (int ii = 0; ii < 4; ++ii)
#pragma unroll
                for (int jj = 0; jj < 4; ++jj)
                    acc[ii][jj] = fmaf(a4[ii], b4[jj], acc[ii][jj]);
        }
        __syncthreads();
    }
#pragma unroll
    for (int ii = 0; ii < 4; ++ii) {
        int m = m0 + ty * 4 + ii;
#pragma unroll
        for (int jj = 0; jj < 4; ++jj) {
            int c = n0 + tx * 4 + jj;
            float val = acc[ii][jj];
            if (c < 512) {
                int h = c >> 6, d = c & 63;
                qo[((h << 10) + m) * 64 + d] = val * 0.125f;
            } else if (c < 1024) {
                int c2 = c - 512, h = c2 >> 6, d = c2 & 63;
                kT[(h * 64 + d) * JPAD + 2 + m] = val;
            } else {
                int c2 = c - 1024, h = c2 >> 6, d = c2 & 63;
                vo[(h * JTOT + 2 + m) * DHEAD + d] = val;
            }
        }
    }
}

// ---------------- fused sim + coordinate descent + PV ----------------
// One wave per (head,row). Single instantiation, wave-uniform t<tmax guards.
// Fixed-shift CD: aM = ln8 - log(sum(exp(zm))), zm = min(s10m, 2*s10m+aM),
// s10m = s*10 - M <= 0. sum in [exp(-~7), 1026] -> no overflow.
__global__ __launch_bounds__(256, 4) void cd_kernel(const float* __restrict__ q,
                                                    const float* __restrict__ kT,
                                                    const float* __restrict__ vv,
                                                    float* __restrict__ ao) {
    __shared__ float qs[4][64];
    __shared__ float ps[4][JPAD];
    int wave = threadIdx.x >> 6, lane = threadIdx.x & 63;
    int idx = (blockIdx.x << 2) + wave;
    int i = 1023 - (idx >> 3);        // longest rows first; block's 4 waves share i
    int h = idx & 7;
    int nvalid = i + 3;               // 2 null kv + causal i+1
    int tmax = (nvalid + 63) >> 6;    // wave-uniform (and block-uniform)

    qs[wave][lane] = q[(((h << 10) + i) << 6) + lane];  // wave-private LDS

    const float* ktb = kT + (size_t)(h << 6) * JPAD + lane;
    float s10m[NT];
    float M = -INFINITY;
#pragma unroll
    for (int t = 0; t < NT; ++t) {
        if (t < tmax) {
            const float* p0 = ktb + (t << 6);
            float a0 = 0.f, a1 = 0.f, a2 = 0.f, a3 = 0.f;
#pragma unroll
            for (int d = 0; d < 64; d += 4) {
                float4 qv = *(const float4*)(&qs[wave][d]);
                a0 = fmaf(qv.x, p0[(size_t)(d + 0) * JPAD], a0);
                a1 = fmaf(qv.y, p0[(size_t)(d + 1) * JPAD], a1);
                a2 = fmaf(qv.z, p0[(size_t)(d + 2) * JPAD], a2);
                a3 = fmaf(qv.w, p0[(size_t)(d + 3) * JPAD], a3);
            }
            int j = lane + (t << 6);
            float sv = ((a0 + a1) + (a2 + a3)) * 10.f;
            s10m[t] = (j < nvalid) ? sv : -INFINITY;
            M = fmaxf(M, s10m[t]);
        }
    }
    M = wave_max64(M);
#pragma unroll
    for (int t = 0; t < NT; ++t)
        if (t < tmax) s10m[t] -= M;   // -inf stays -inf

    const float LOGK = 2.0794415416798357f;  // ln 8
    // iteration 1 analytic: sb == 0 on mask -> lse = log(nvalid)
    float aM = LOGK - __logf((float)nvalid) + M;
#pragma unroll 1
    for (int it = 1; it < 50; ++it) {
        float sc0 = 0.f, sc1 = 0.f, sc2 = 0.f, sc3 = 0.f;
#pragma unroll
        for (int t = 0; t < NT; ++t) {
            if (t < tmax) {
                float e = __expf(fminf(s10m[t], fmaf(s10m[t], 2.f, aM)));
                if ((t & 3) == 0) sc0 += e;
                else if ((t & 3) == 1) sc1 += e;
                else if ((t & 3) == 2) sc2 += e;
                else sc3 += e;
            }
        }
        float sum = wave_sum64((sc0 + sc1) + (sc2 + sc3));
        float aMn = LOGK - __logf(sum);
        bool conv = (__float_as_int(aMn) == __float_as_int(aM));  // wave-uniform
        aM = aMn;
        if (conv) break;   // bitwise fixed point: remaining iterations are identity
    }

    // final scores -> LDS (masked lanes in last slot give exp(-inf)=0)
#pragma unroll
    for (int t = 0; t < NT; ++t) {
        if (t < tmax) {
            float tmp = s10m[t] + aM;
            ps[wave][lane + (t << 6)] = __expf(tmp + fminf(0.f, tmp));
        }
    }

    // PV: lane = d, loop j
    const float* vb = vv + (size_t)h * JTOT * DHEAD + lane;
    const float* psw = ps[wave];
    float b0 = 0.f, b1 = 0.f, b2 = 0.f, b3 = 0.f;
    int j = 0;
    for (; j + 4 <= nvalid; j += 4) {
        float4 p4 = *(const float4*)(psw + j);
        b0 = fmaf(p4.x, vb[(size_t)(j + 0) * 64], b0);
        b1 = fmaf(p4.y, vb[(size_t)(j + 1) * 64], b1);
        b2 = fmaf(p4.z, vb[(size_t)(j + 2) * 64], b2);
        b3 = fmaf(p4.w, vb[(size_t)(j + 3) * 64], b3);
    }
    for (; j < nvalid; ++j) b0 = fmaf(psw[j], vb[(size_t)j * 64], b0);
    ao[(i << 9) + (h << 6) + lane] = (b0 + b1) + (b2 + b3);
}

// ---------------- out GEMM: ao[1024][512] @ w_out[512][512] -> d_out ----------------
__global__ __launch_bounds__(256) void out_gemm(const float* __restrict__ A,
                                                const float* __restrict__ B,
                                                float* __restrict__ C) {
    const int K = 512, Nn = 512;
    __shared__ float As[16][64];
    __shared__ float Bs[16][64];
    int tid = threadIdx.x;
    int m0 = blockIdx.x * 64, n0 = blockIdx.y * 64;
    int ty = tid >> 4, tx = tid & 15;
    int lam = tid >> 2, lak = (tid & 3) << 2;
    int lbk = tid >> 4, lbn = (tid & 15) << 2;
    float acc[4][4] = {};
    for (int k0 = 0; k0 < K; k0 += 16) {
        float4 av = *(const float4*)(A + (m0 + lam) * K + k0 + lak);
        float4 bv = *(const float4*)(B + (size_t)(k0 + lbk) * Nn + n0 + lbn);
        As[lak + 0][lam] = av.x; As[lak + 1][lam] = av.y;
        As[lak + 2][lam] = av.z; As[lak + 3][lam] = av.w;
        *(float4*)&Bs[lbk][lbn] = bv;
        __syncthreads();
#pragma unroll
        for (int kk = 0; kk < 16; ++kk) {
            float a4[4], b4[4];
#pragma unroll
            for (int u = 0; u < 4; ++u) a4[u] = As[kk][ty * 4 + u];
#pragma unroll
            for (int u = 0; u < 4; ++u) b4[u] = Bs[kk][tx * 4 + u];
#pragma unroll
            for (int ii = 0; ii < 4; ++ii)
#pragma unroll
                for (int jj = 0; jj < 4; ++jj)
                    acc[ii][jj] = fmaf(a4[ii], b4[jj], acc[ii][jj]);
        }
        __syncthreads();
    }
#pragma unroll
    for (int ii = 0; ii < 4; ++ii) {
        int m = m0 + ty * 4 + ii;
#pragma unroll
        for (int jj = 0; jj < 4; ++jj) {
            int c = n0 + tx * 4 + jj;
            C[m * Nn + c] = acc[ii][jj];
        }
    }
}

extern "C" void kernel_launch(void* const* d_in, const int* in_sizes, int n_in,
                              void* d_out, int out_size, void* d_ws, size_t ws_size,
                              hipStream_t stream) {
    const float* x      = (const float*)d_in[0];
    const float* w_qkv  = (const float*)d_in[1];
    const float* w_out  = (const float*)d_in[2];
    const float* nullkv = (const float*)d_in[3];
    const float* ln_g   = (const float*)d_in[4];
    const float* ln_b   = (const float*)d_in[5];
    float* ws = (float*)d_ws;

    float* xn = ws;                                  // 1024*512
    float* q  = xn + 1024 * 512;                     // 8*1024*64
    float* kT = q + 8 * 1024 * 64;                   // 8*64*JPAD
    float* vv = kT + 8 * 64 * JPAD;                  // 8*JTOT*64
    float* ao = vv + 8 * JTOT * 64;                  // 1024*512
    float* out = (float*)d_out;

    hipLaunchKernelGGL(ln_kernel, dim3(1024), dim3(128), 0, stream, x, ln_g, ln_b, xn);
    hipLaunchKernelGGL(nullkv_kernel, dim3(4), dim3(256), 0, stream, nullkv, kT, vv);
    hipLaunchKernelGGL(qkv_gemm, dim3(16, 24), dim3(256), 0, stream, xn, w_qkv, q, kT, vv);
    hipLaunchKernelGGL(cd_kernel, dim3(2048), dim3(256), 0, stream, q, kT, vv, ao);
    hipLaunchKernelGGL(out_gemm, dim3(16, 8), dim3(256), 0, stream, ao, w_out, out);
}

// Round 4
// 240.850 us; speedup vs baseline: 4.7732x; 1.1006x over previous
//
#include <hip/hip_runtime.h>
#include <math.h>

#define NTOK 1024
#define DIMM 512
#define NHEAD 8
#define DHEAD 64
#define JTOT 1026      // NTOK + 2 null kv
#define JPAD 1088      // 17*64 padded kT row
#define LOGK 2.0794415416798357f

// ---------------- wave reductions (64 lanes) ----------------
__device__ __forceinline__ float wave_sum64(float x) {
    x += __int_as_float(__builtin_amdgcn_ds_swizzle(__float_as_int(x), 0x041F)); // ^1
    x += __int_as_float(__builtin_amdgcn_ds_swizzle(__float_as_int(x), 0x081F)); // ^2
    x += __int_as_float(__builtin_amdgcn_ds_swizzle(__float_as_int(x), 0x101F)); // ^4
    x += __int_as_float(__builtin_amdgcn_ds_swizzle(__float_as_int(x), 0x201F)); // ^8
    x += __int_as_float(__builtin_amdgcn_ds_swizzle(__float_as_int(x), 0x401F)); // ^16
    x += __shfl_xor(x, 32);
    return x;
}
__device__ __forceinline__ float wave_max64(float x) {
    x = fmaxf(x, __int_as_float(__builtin_amdgcn_ds_swizzle(__float_as_int(x), 0x041F)));
    x = fmaxf(x, __int_as_float(__builtin_amdgcn_ds_swizzle(__float_as_int(x), 0x081F)));
    x = fmaxf(x, __int_as_float(__builtin_amdgcn_ds_swizzle(__float_as_int(x), 0x101F)));
    x = fmaxf(x, __int_as_float(__builtin_amdgcn_ds_swizzle(__float_as_int(x), 0x201F)));
    x = fmaxf(x, __int_as_float(__builtin_amdgcn_ds_swizzle(__float_as_int(x), 0x401F)));
    x = fmaxf(x, __shfl_xor(x, 32));
    return x;
}

// ---------------- LayerNorm ----------------
__global__ __launch_bounds__(128) void ln_kernel(const float* __restrict__ x,
                                                 const float* __restrict__ g,
                                                 const float* __restrict__ bb,
                                                 float* __restrict__ xn) {
    int row = blockIdx.x, tid = threadIdx.x;
    float4 v = ((const float4*)(x + row * DIMM))[tid];
    float s  = v.x + v.y + v.z + v.w;
    float ss = fmaf(v.x, v.x, fmaf(v.y, v.y, fmaf(v.z, v.z, v.w * v.w)));
#pragma unroll
    for (int off = 32; off; off >>= 1) {
        s  += __shfl_down(s, off);
        ss += __shfl_down(ss, off);
    }
    __shared__ float sm[4];
    if ((tid & 63) == 0) { sm[(tid >> 6) * 2] = s; sm[(tid >> 6) * 2 + 1] = ss; }
    __syncthreads();
    s = sm[0] + sm[2]; ss = sm[1] + sm[3];
    float mu   = s * (1.f / DIMM);
    float var  = ss * (1.f / DIMM) - mu * mu;
    float rstd = 1.f / sqrtf(var + 1e-5f);
    float4 gv = ((const float4*)g)[tid];
    float4 bv = ((const float4*)bb)[tid];
    float4 o;
    o.x = (v.x - mu) * rstd * gv.x + bv.x;
    o.y = (v.y - mu) * rstd * gv.y + bv.y;
    o.z = (v.z - mu) * rstd * gv.z + bv.z;
    o.w = (v.w - mu) * rstd * gv.w + bv.w;
    ((float4*)(xn + row * DIMM))[tid] = o;
}

// ---------------- null kv fill ----------------
__global__ __launch_bounds__(256) void nullkv_kernel(const float* __restrict__ nkv,
                                                     float* __restrict__ kT,
                                                     float* __restrict__ vv) {
    int tid = blockIdx.x * 256 + threadIdx.x;
    if (tid >= NHEAD * 2 * DHEAD) return;
    int d = tid & 63, p = (tid >> 6) & 1, h = tid >> 7;
    kT[(h * DHEAD + d) * JPAD + p] = nkv[((0 * NHEAD + h) * 2 + p) * DHEAD + d];
    vv[(h * JTOT + p) * DHEAD + d] = nkv[((1 * NHEAD + h) * 2 + p) * DHEAD + d];
}

// ============ split-K QKV GEMM: writes partials P[z][1024][1536] ============
__global__ __launch_bounds__(256) void qkv_gemm_part(const float* __restrict__ A,
                                                     const float* __restrict__ B,
                                                     float* __restrict__ P) {
    const int K = 512, Nn = 1536, KH = 256;
    __shared__ float As[16][64];
    __shared__ float Bs[16][64];
    int tid = threadIdx.x;
    int m0 = blockIdx.x * 64, n0 = blockIdx.y * 64, kb = blockIdx.z * KH;
    int ty = tid >> 4, tx = tid & 15;
    int lam = tid >> 2, lak = (tid & 3) << 2;
    int lbk = tid >> 4, lbn = (tid & 15) << 2;
    float acc[4][4] = {};
    for (int k0 = 0; k0 < KH; k0 += 16) {
        float4 av = *(const float4*)(A + (m0 + lam) * K + kb + k0 + lak);
        float4 bv = *(const float4*)(B + (size_t)(kb + k0 + lbk) * Nn + n0 + lbn);
        As[lak + 0][lam] = av.x; As[lak + 1][lam] = av.y;
        As[lak + 2][lam] = av.z; As[lak + 3][lam] = av.w;
        *(float4*)&Bs[lbk][lbn] = bv;
        __syncthreads();
#pragma unroll
        for (int kk = 0; kk < 16; ++kk) {
            float a4[4], b4[4];
#pragma unroll
            for (int u = 0; u < 4; ++u) a4[u] = As[kk][ty * 4 + u];
#pragma unroll
            for (int u = 0; u < 4; ++u) b4[u] = Bs[kk][tx * 4 + u];
#pragma unroll
            for (int ii = 0; ii < 4; ++ii)
#pragma unroll
                for (int jj = 0; jj < 4; ++jj)
                    acc[ii][jj] = fmaf(a4[ii], b4[jj], acc[ii][jj]);
        }
        __syncthreads();
    }
    float* Pz = P + (size_t)blockIdx.z * 1024 * 1536;
#pragma unroll
    for (int ii = 0; ii < 4; ++ii) {
        int m = m0 + ty * 4 + ii;
#pragma unroll
        for (int jj = 0; jj < 4; ++jj)
            Pz[(size_t)m * 1536 + n0 + tx * 4 + jj] = acc[ii][jj];
    }
}

// scatter P0+P1 -> q (scaled), kT, vv.  grid (6, 1024)
__global__ __launch_bounds__(256) void qkv_scatter(const float* __restrict__ P0,
                                                   const float* __restrict__ P1,
                                                   float* __restrict__ qo,
                                                   float* __restrict__ kT,
                                                   float* __restrict__ vo) {
    int c = blockIdx.x * 256 + threadIdx.x;
    int m = blockIdx.y;
    size_t idx = (size_t)m * 1536 + c;
    float val = P0[idx] + P1[idx];
    if (c < 512) {
        int h = c >> 6, d = c & 63;
        qo[((h << 10) + m) * 64 + d] = val * 0.125f;
    } else if (c < 1024) {
        int c2 = c - 512, h = c2 >> 6, d = c2 & 63;
        kT[(h * 64 + d) * JPAD + 2 + m] = val;
    } else {
        int c2 = c - 1024, h = c2 >> 6, d = c2 & 63;
        vo[(h * JTOT + 2 + m) * DHEAD + d] = val;
    }
}

// ============ monolithic fallback QKV GEMM (round-3 proven) ============
__global__ __launch_bounds__(256) void qkv_gemm_mono(const float* __restrict__ A,
                                                     const float* __restrict__ B,
                                                     float* __restrict__ qo,
                                                     float* __restrict__ kT,
                                                     float* __restrict__ vo) {
    const int K = 512, Nn = 1536;
    __shared__ float As[16][64];
    __shared__ float Bs[16][64];
    int tid = threadIdx.x;
    int m0 = blockIdx.x * 64, n0 = blockIdx.y * 64;
    int ty = tid >> 4, tx = tid & 15;
    int lam = tid >> 2, lak = (tid & 3) << 2;
    int lbk = tid >> 4, lbn = (tid & 15) << 2;
    float acc[4][4] = {};
    for (int k0 = 0; k0 < K; k0 += 16) {
        float4 av = *(const float4*)(A + (m0 + lam) * K + k0 + lak);
        float4 bv = *(const float4*)(B + (size_t)(k0 + lbk) * Nn + n0 + lbn);
        As[lak + 0][lam] = av.x; As[lak + 1][lam] = av.y;
        As[lak + 2][lam] = av.z; As[lak + 3][lam] = av.w;
        *(float4*)&Bs[lbk][lbn] = bv;
        __syncthreads();
#pragma unroll
        for (int kk = 0; kk < 16; ++kk) {
            float a4[4], b4[4];
#pragma unroll
            for (int u = 0; u < 4; ++u) a4[u] = As[kk][ty * 4 + u];
#pragma unroll
            for (int u = 0; u < 4; ++u) b4[u] = Bs[kk][tx * 4 + u];
#pragma unroll
            for (int ii = 0; ii < 4; ++ii)
#pragma unroll
                for (int jj = 0; jj < 4; ++jj)
                    acc[ii][jj] = fmaf(a4[ii], b4[jj], acc[ii][jj]);
        }
        __syncthreads();
    }
#pragma unroll
    for (int ii = 0; ii < 4; ++ii) {
        int m = m0 + ty * 4 + ii;
#pragma unroll
        for (int jj = 0; jj < 4; ++jj) {
            int c = n0 + tx * 4 + jj;
            float val = acc[ii][jj];
            if (c < 512) {
                int h = c >> 6, d = c & 63;
                qo[((h << 10) + m) * 64 + d] = val * 0.125f;
            } else if (c < 1024) {
                int c2 = c - 512, h = c2 >> 6, d = c2 & 63;
                kT[(h * 64 + d) * JPAD + 2 + m] = val;
            } else {
                int c2 = c - 1024, h = c2 >> 6, d = c2 & 63;
                vo[(h * JTOT + 2 + m) * DHEAD + d] = val;
            }
        }
    }
}

// ---------------- fused sim + CD + PV, complementary row pairs ----------------
// Wave handles rows (iA=1023-ip, iB=ip) of head h: constant work per wave.
// Shifted CD: g <- LOGK - log(sum(min(E, E2*e^g))), E=exp(s10-M)<=1.
__global__ __launch_bounds__(256, 4) void cd_pair_kernel(const float* __restrict__ q,
                                                         const float* __restrict__ kT,
                                                         const float* __restrict__ vv,
                                                         float* __restrict__ ao) {
    __shared__ float qs[4][2][64];
    __shared__ float psA[4][1280];
    __shared__ float psB[4][768];
    int wave = threadIdx.x >> 6, lane = threadIdx.x & 63;
    int p = (blockIdx.x << 2) + wave;
    int h = p >> 9, ip = p & 511;
    int iA = 1023 - ip, iB = ip;
    int nvA = iA + 3, nvB = iB + 3;

    qs[wave][0][lane] = q[(((h << 10) + iA) << 6) + lane];
    qs[wave][1][lane] = q[(((h << 10) + iB) << 6) + lane];

    // ---- scores: lane owns j = 4*lane + c + 256*t ----
    const float* kbase = kT + (size_t)(h << 6) * JPAD + (lane << 2);
    float4 sA[5] = {}; float4 sB[3] = {};
    for (int d4 = 0; d4 < 64; d4 += 4) {
        float4 qa4 = *(const float4*)&qs[wave][0][d4];
        float4 qb4 = *(const float4*)&qs[wave][1][d4];
#pragma unroll
        for (int dd = 0; dd < 4; ++dd) {
            float qa = ((const float*)&qa4)[dd];
            float qb = ((const float*)&qb4)[dd];
            const float* kd = kbase + (size_t)(d4 + dd) * JPAD;
            float4 kv[5];
#pragma unroll
            for (int t = 0; t < 5; ++t) kv[t] = *(const float4*)(kd + (t << 8));
#pragma unroll
            for (int t = 0; t < 5; ++t) {
                sA[t].x = fmaf(qa, kv[t].x, sA[t].x);
                sA[t].y = fmaf(qa, kv[t].y, sA[t].y);
                sA[t].z = fmaf(qa, kv[t].z, sA[t].z);
                sA[t].w = fmaf(qa, kv[t].w, sA[t].w);
            }
#pragma unroll
            for (int t = 0; t < 3; ++t) {
                sB[t].x = fmaf(qb, kv[t].x, sB[t].x);
                sB[t].y = fmaf(qb, kv[t].y, sB[t].y);
                sB[t].z = fmaf(qb, kv[t].z, sB[t].z);
                sB[t].w = fmaf(qb, kv[t].w, sB[t].w);
            }
        }
    }

    // ---- mask (x10), row maxes ----
    int jb = lane << 2;
    float mA = -INFINITY, mB = -INFINITY;
#pragma unroll
    for (int t = 0; t < 5; ++t) {
        float* sp = (float*)&sA[t];
#pragma unroll
        for (int c = 0; c < 4; ++c) {
            int j = jb + c + (t << 8);
            float v = (j < nvA) ? sp[c] * 10.f : -INFINITY;
            sp[c] = v; mA = fmaxf(mA, v);
        }
    }
#pragma unroll
    for (int t = 0; t < 3; ++t) {
        float* sp = (float*)&sB[t];
#pragma unroll
        for (int c = 0; c < 4; ++c) {
            int j = jb + c + (t << 8);
            float v = (j < nvB) ? sp[c] * 10.f : -INFINITY;
            sp[c] = v; mB = fmaxf(mB, v);
        }
    }
    mA = wave_max64(mA); mB = wave_max64(mB);

    // ---- E tables (masked -> 0) ----
    float4 EA[5], E2A[5], EB[3], E2B[3];
#pragma unroll
    for (int t = 0; t < 5; ++t) {
        float* sp = (float*)&sA[t]; float* ep = (float*)&EA[t]; float* e2p = (float*)&E2A[t];
#pragma unroll
        for (int c = 0; c < 4; ++c) { float e = __expf(sp[c] - mA); ep[c] = e; e2p[c] = e * e; }
    }
#pragma unroll
    for (int t = 0; t < 3; ++t) {
        float* sp = (float*)&sB[t]; float* ep = (float*)&EB[t]; float* e2p = (float*)&E2B[t];
#pragma unroll
        for (int c = 0; c < 4; ++c) { float e = __expf(sp[c] - mB); ep[c] = e; e2p[c] = e * e; }
    }

    // ---- CD loop (step 1 analytic; 49 more) ----
    float gA = LOGK - __logf((float)nvA) + mA;
    float gB = LOGK - __logf((float)nvB) + mB;
#pragma unroll 1
    for (int it = 1; it < 50; ++it) {
        float egA = __expf(fminf(gA, 80.f));
        float egB = __expf(fminf(gB, 80.f));
        float4 aA = {0.f, 0.f, 0.f, 0.f}, aB = {0.f, 0.f, 0.f, 0.f};
#pragma unroll
        for (int t = 0; t < 5; ++t) {
            aA.x += fminf(((float*)&EA[t])[0], ((float*)&E2A[t])[0] * egA);
            aA.y += fminf(((float*)&EA[t])[1], ((float*)&E2A[t])[1] * egA);
            aA.z += fminf(((float*)&EA[t])[2], ((float*)&E2A[t])[2] * egA);
            aA.w += fminf(((float*)&EA[t])[3], ((float*)&E2A[t])[3] * egA);
        }
#pragma unroll
        for (int t = 0; t < 3; ++t) {
            aB.x += fminf(((float*)&EB[t])[0], ((float*)&E2B[t])[0] * egB);
            aB.y += fminf(((float*)&EB[t])[1], ((float*)&E2B[t])[1] * egB);
            aB.z += fminf(((float*)&EB[t])[2], ((float*)&E2B[t])[2] * egB);
            aB.w += fminf(((float*)&EB[t])[3], ((float*)&E2B[t])[3] * egB);
        }
        float sumA = wave_sum64((aA.x + aA.y) + (aA.z + aA.w));
        float sumB = wave_sum64((aB.x + aB.y) + (aB.z + aB.w));
        float gA2 = LOGK - __logf(sumA);
        float gB2 = LOGK - __logf(sumB);
        bool conv = (__float_as_int(gA2) == __float_as_int(gA)) &&
                    (__float_as_int(gB2) == __float_as_int(gB));
        gA = gA2; gB = gB2;
        if (conv) break;
    }

    // ---- final p -> LDS ----
    {
        float egA = __expf(fminf(gA, 80.f));
        float egB = __expf(fminf(gB, 80.f));
#pragma unroll
        for (int t = 0; t < 5; ++t) {
            float4 pv;
            pv.x = ((float*)&EA[t])[0] * egA; pv.x = pv.x * fminf(1.f, pv.x);
            pv.y = ((float*)&EA[t])[1] * egA; pv.y = pv.y * fminf(1.f, pv.y);
            pv.z = ((float*)&EA[t])[2] * egA; pv.z = pv.z * fminf(1.f, pv.z);
            pv.w = ((float*)&EA[t])[3] * egA; pv.w = pv.w * fminf(1.f, pv.w);
            *(float4*)&psA[wave][jb + (t << 8)] = pv;
        }
#pragma unroll
        for (int t = 0; t < 3; ++t) {
            float4 pv;
            pv.x = ((float*)&EB[t])[0] * egB; pv.x = pv.x * fminf(1.f, pv.x);
            pv.y = ((float*)&EB[t])[1] * egB; pv.y = pv.y * fminf(1.f, pv.y);
            pv.z = ((float*)&EB[t])[2] * egB; pv.z = pv.z * fminf(1.f, pv.z);
            pv.w = ((float*)&EB[t])[3] * egB; pv.w = pv.w * fminf(1.f, pv.w);
            *(float4*)&psB[wave][jb + (t << 8)] = pv;
        }
    }

    // ---- PV: lane = d; joint prefix (v loads shared), then A-only ----
    const float* vb = vv + (size_t)h * JTOT * DHEAD + lane;
    float oA0 = 0.f, oA1 = 0.f, oB0 = 0.f, oB1 = 0.f;
    int nB4 = (nvB + 3) & ~3;
    int nA4 = (nvA + 3) & ~3;
    int j = 0;
    for (; j < nB4; j += 4) {
        float4 pa = *(const float4*)&psA[wave][j];
        float4 pb = *(const float4*)&psB[wave][j];
        float v0 = vb[(size_t)(j + 0) * 64];
        float v1 = vb[(size_t)(j + 1) * 64];
        float v2 = vb[(size_t)(j + 2) * 64];
        float v3 = vb[(size_t)(j + 3) * 64];
        oA0 = fmaf(pa.x, v0, oA0); oA1 = fmaf(pa.y, v1, oA1);
        oA0 = fmaf(pa.z, v2, oA0); oA1 = fmaf(pa.w, v3, oA1);
        oB0 = fmaf(pb.x, v0, oB0); oB1 = fmaf(pb.y, v1, oB1);
        oB0 = fmaf(pb.z, v2, oB0); oB1 = fmaf(pb.w, v3, oB1);
    }
    for (; j < nA4; j += 4) {
        float4 pa = *(const float4*)&psA[wave][j];
        float v0 = vb[(size_t)(j + 0) * 64];
        float v1 = vb[(size_t)(j + 1) * 64];
        float v2 = vb[(size_t)(j + 2) * 64];
        float v3 = vb[(size_t)(j + 3) * 64];
        oA0 = fmaf(pa.x, v0, oA0); oA1 = fmaf(pa.y, v1, oA1);
        oA0 = fmaf(pa.z, v2, oA0); oA1 = fmaf(pa.w, v3, oA1);
    }
    ao[(iA << 9) + (h << 6) + lane] = oA0 + oA1;
    ao[(iB << 9) + (h << 6) + lane] = oB0 + oB1;
}

// ============ split-K out GEMM ============
__global__ __launch_bounds__(256) void out_gemm_part(const float* __restrict__ A,
                                                     const float* __restrict__ B,
                                                     float* __restrict__ Po) {
    const int K = 512, Nn = 512, KH = 256;
    __shared__ float As[16][64];
    __shared__ float Bs[16][64];
    int tid = threadIdx.x;
    int m0 = blockIdx.x * 64, n0 = blockIdx.y * 64, kb = blockIdx.z * KH;
    int ty = tid >> 4, tx = tid & 15;
    int lam = tid >> 2, lak = (tid & 3) << 2;
    int lbk = tid >> 4, lbn = (tid & 15) << 2;
    float acc[4][4] = {};
    for (int k0 = 0; k0 < KH; k0 += 16) {
        float4 av = *(const float4*)(A + (m0 + lam) * K + kb + k0 + lak);
        float4 bv = *(const float4*)(B + (size_t)(kb + k0 + lbk) * Nn + n0 + lbn);
        As[lak + 0][lam] = av.x; As[lak + 1][lam] = av.y;
        As[lak + 2][lam] = av.z; As[lak + 3][lam] = av.w;
        *(float4*)&Bs[lbk][lbn] = bv;
        __syncthreads();
#pragma unroll
        for (int kk = 0; kk < 16; ++kk) {
            float a4[4], b4[4];
#pragma unroll
            for (int u = 0; u < 4; ++u) a4[u] = As[kk][ty * 4 + u];
#pragma unroll
            for (int u = 0; u < 4; ++u) b4[u] = Bs[kk][tx * 4 + u];
#pragma unroll
            for (int ii = 0; ii < 4; ++ii)
#pragma unroll
                for (int jj = 0; jj < 4; ++jj)
                    acc[ii][jj] = fmaf(a4[ii], b4[jj], acc[ii][jj]);
        }
        __syncthreads();
    }
    float* Pz = Po + (size_t)blockIdx.z * 1024 * 512;
#pragma unroll
    for (int ii = 0; ii < 4; ++ii) {
        int m = m0 + ty * 4 + ii;
#pragma unroll
        for (int jj = 0; jj < 4; ++jj)
            Pz[(size_t)m * 512 + n0 + tx * 4 + jj] = acc[ii][jj];
    }
}

__global__ __launch_bounds__(256) void out_combine(const float* __restrict__ P0,
                                                   const float* __restrict__ P1,
                                                   float* __restrict__ C) {
    int g = blockIdx.x * 256 + threadIdx.x;
    C[g] = P0[g] + P1[g];
}

// ============ monolithic fallback out GEMM ============
__global__ __launch_bounds__(256) void out_gemm_mono(const float* __restrict__ A,
                                                     const float* __restrict__ B,
                                                     float* __restrict__ C) {
    const int K = 512, Nn = 512;
    __shared__ float As[16][64];
    __shared__ float Bs[16][64];
    int tid = threadIdx.x;
    int m0 = blockIdx.x * 64, n0 = blockIdx.y * 64;
    int ty = tid >> 4, tx = tid & 15;
    int lam = tid >> 2, lak = (tid & 3) << 2;
    int lbk = tid >> 4, lbn = (tid & 15) << 2;
    float acc[4][4] = {};
    for (int k0 = 0; k0 < K; k0 += 16) {
        float4 av = *(const float4*)(A + (m0 + lam) * K + k0 + lak);
        float4 bv = *(const float4*)(B + (size_t)(k0 + lbk) * Nn + n0 + lbn);
        As[lak + 0][lam] = av.x; As[lak + 1][lam] = av.y;
        As[lak + 2][lam] = av.z; As[lak + 3][lam] = av.w;
        *(float4*)&Bs[lbk][lbn] = bv;
        __syncthreads();
#pragma unroll
        for (int kk = 0; kk < 16; ++kk) {
            float a4[4], b4[4];
#pragma unroll
            for (int u = 0; u < 4; ++u) a4[u] = As[kk][ty * 4 + u];
#pragma unroll
            for (int u = 0; u < 4; ++u) b4[u] = Bs[kk][tx * 4 + u];
#pragma unroll
            for (int ii = 0; ii < 4; ++ii)
#pragma unroll
                for (int jj = 0; jj < 4; ++jj)
                    acc[ii][jj] = fmaf(a4[ii], b4[jj], acc[ii][jj]);
        }
        __syncthreads();
    }
#pragma unroll
    for (int ii = 0; ii < 4; ++ii) {
        int m = m0 + ty * 4 + ii;
#pragma unroll
        for (int jj = 0; jj < 4; ++jj)
            C[(m0 + ty * 4 + ii) * Nn + n0 + tx * 4 + jj] = acc[ii][jj];
    }
}

extern "C" void kernel_launch(void* const* d_in, const int* in_sizes, int n_in,
                              void* d_out, int out_size, void* d_ws, size_t ws_size,
                              hipStream_t stream) {
    const float* x      = (const float*)d_in[0];
    const float* w_qkv  = (const float*)d_in[1];
    const float* w_out  = (const float*)d_in[2];
    const float* nullkv = (const float*)d_in[3];
    const float* ln_g   = (const float*)d_in[4];
    const float* ln_b   = (const float*)d_in[5];
    float* ws = (float*)d_ws;
    float* out = (float*)d_out;

    const size_t XN = 512 * 1024;            // 524288
    const size_t QSZ = 512 * 1024;
    const size_t KTSZ = (size_t)NHEAD * 64 * JPAD;   // 557056
    const size_t VVSZ = (size_t)NHEAD * JTOT * 64;   // 525312
    const size_t PSZ = (size_t)1024 * 1536;          // per partial

    float* xn = ws;
    float* q  = xn + XN;
    float* kT = q + QSZ;
    float* vv = kT + KTSZ;

    const size_t needSplit = (XN + QSZ + KTSZ + VVSZ + 2 * PSZ) * 4;

    hipLaunchKernelGGL(ln_kernel, dim3(1024), dim3(128), 0, stream, x, ln_g, ln_b, xn);
    hipLaunchKernelGGL(nullkv_kernel, dim3(4), dim3(256), 0, stream, nullkv, kT, vv);

    if (ws_size >= needSplit) {
        float* P0 = vv + VVSZ;
        float* P1 = P0 + PSZ;
        float* ao = P0;          // alias: P dead before cd writes ao
        float* Po0 = xn;         // alias: xn dead after qkv
        float* Po1 = q;          // alias: q dead after cd
        hipLaunchKernelGGL(qkv_gemm_part, dim3(16, 24, 2), dim3(256), 0, stream, xn, w_qkv, P0);
        hipLaunchKernelGGL(qkv_scatter, dim3(6, 1024), dim3(256), 0, stream, P0, P1, q, kT, vv);
        hipLaunchKernelGGL(cd_pair_kernel, dim3(1024), dim3(256), 0, stream, q, kT, vv, ao);
        hipLaunchKernelGGL(out_gemm_part, dim3(16, 8, 2), dim3(256), 0, stream, ao, w_out, Po0);
        hipLaunchKernelGGL(out_combine, dim3(2048), dim3(256), 0, stream, Po0, Po1, out);
    } else {
        float* ao = vv + VVSZ;
        hipLaunchKernelGGL(qkv_gemm_mono, dim3(16, 24), dim3(256), 0, stream, xn, w_qkv, q, kT, vv);
        hipLaunchKernelGGL(cd_pair_kernel, dim3(1024), dim3(256), 0, stream, q, kT, vv, ao);
        hipLaunchKernelGGL(out_gemm_mono, dim3(16, 8), dim3(256), 0, stream, ao, w_out, out);
    }
}

// Round 5
// 230.901 us; speedup vs baseline: 4.9789x; 1.0431x over previous
//
#include <hip/hip_runtime.h>
#include <math.h>

#define NTOK 1024
#define DIMM 512
#define NHEAD 8
#define DHEAD 64
#define JTOT 1026      // NTOK + 2 null kv
#define JPAD 1088      // 17*64 padded kT row
#define VSTR 1056      // v rows per head (padded)
#define PROW 1056      // pbuf row stride (floats)
#define LOGK 2.0794415416798357f

// ---------------- DPP wave reductions (64 lanes), result broadcast ----------------
__device__ __forceinline__ float dpp_sum64(float x) {
    int v;
    v = __builtin_amdgcn_update_dpp(0, __float_as_int(x), 0x111, 0xf, 0xf, true); x += __int_as_float(v);
    v = __builtin_amdgcn_update_dpp(0, __float_as_int(x), 0x112, 0xf, 0xf, true); x += __int_as_float(v);
    v = __builtin_amdgcn_update_dpp(0, __float_as_int(x), 0x114, 0xf, 0xf, true); x += __int_as_float(v);
    v = __builtin_amdgcn_update_dpp(0, __float_as_int(x), 0x118, 0xf, 0xf, true); x += __int_as_float(v);
    v = __builtin_amdgcn_update_dpp(0, __float_as_int(x), 0x142, 0xa, 0xf, true); x += __int_as_float(v);
    v = __builtin_amdgcn_update_dpp(0, __float_as_int(x), 0x143, 0xc, 0xf, true); x += __int_as_float(v);
    return __int_as_float(__builtin_amdgcn_readlane(__float_as_int(x), 63));
}
__device__ __forceinline__ float dpp_max64(float x) {
    int v;
    v = __builtin_amdgcn_update_dpp(__float_as_int(x), __float_as_int(x), 0x111, 0xf, 0xf, false); x = fmaxf(x, __int_as_float(v));
    v = __builtin_amdgcn_update_dpp(__float_as_int(x), __float_as_int(x), 0x112, 0xf, 0xf, false); x = fmaxf(x, __int_as_float(v));
    v = __builtin_amdgcn_update_dpp(__float_as_int(x), __float_as_int(x), 0x114, 0xf, 0xf, false); x = fmaxf(x, __int_as_float(v));
    v = __builtin_amdgcn_update_dpp(__float_as_int(x), __float_as_int(x), 0x118, 0xf, 0xf, false); x = fmaxf(x, __int_as_float(v));
    v = __builtin_amdgcn_update_dpp(__float_as_int(x), __float_as_int(x), 0x142, 0xa, 0xf, false); x = fmaxf(x, __int_as_float(v));
    v = __builtin_amdgcn_update_dpp(__float_as_int(x), __float_as_int(x), 0x143, 0xc, 0xf, false); x = fmaxf(x, __int_as_float(v));
    return __int_as_float(__builtin_amdgcn_readlane(__float_as_int(x), 63));
}

// legacy swizzle reductions (fallback kernel)
__device__ __forceinline__ float wave_sum64(float x) {
    x += __int_as_float(__builtin_amdgcn_ds_swizzle(__float_as_int(x), 0x041F));
    x += __int_as_float(__builtin_amdgcn_ds_swizzle(__float_as_int(x), 0x081F));
    x += __int_as_float(__builtin_amdgcn_ds_swizzle(__float_as_int(x), 0x101F));
    x += __int_as_float(__builtin_amdgcn_ds_swizzle(__float_as_int(x), 0x201F));
    x += __int_as_float(__builtin_amdgcn_ds_swizzle(__float_as_int(x), 0x401F));
    x += __shfl_xor(x, 32);
    return x;
}
__device__ __forceinline__ float wave_max64(float x) {
    x = fmaxf(x, __int_as_float(__builtin_amdgcn_ds_swizzle(__float_as_int(x), 0x041F)));
    x = fmaxf(x, __int_as_float(__builtin_amdgcn_ds_swizzle(__float_as_int(x), 0x081F)));
    x = fmaxf(x, __int_as_float(__builtin_amdgcn_ds_swizzle(__float_as_int(x), 0x101F)));
    x = fmaxf(x, __int_as_float(__builtin_amdgcn_ds_swizzle(__float_as_int(x), 0x201F)));
    x = fmaxf(x, __int_as_float(__builtin_amdgcn_ds_swizzle(__float_as_int(x), 0x401F)));
    x = fmaxf(x, __shfl_xor(x, 32));
    return x;
}

// ---------------- LayerNorm ----------------
__global__ __launch_bounds__(128) void ln_kernel(const float* __restrict__ x,
                                                 const float* __restrict__ g,
                                                 const float* __restrict__ bb,
                                                 float* __restrict__ xn) {
    int row = blockIdx.x, tid = threadIdx.x;
    float4 v = ((const float4*)(x + row * DIMM))[tid];
    float s  = v.x + v.y + v.z + v.w;
    float ss = fmaf(v.x, v.x, fmaf(v.y, v.y, fmaf(v.z, v.z, v.w * v.w)));
#pragma unroll
    for (int off = 32; off; off >>= 1) {
        s  += __shfl_down(s, off);
        ss += __shfl_down(ss, off);
    }
    __shared__ float sm[4];
    if ((tid & 63) == 0) { sm[(tid >> 6) * 2] = s; sm[(tid >> 6) * 2 + 1] = ss; }
    __syncthreads();
    s = sm[0] + sm[2]; ss = sm[1] + sm[3];
    float mu   = s * (1.f / DIMM);
    float var  = ss * (1.f / DIMM) - mu * mu;
    float rstd = 1.f / sqrtf(var + 1e-5f);
    float4 gv = ((const float4*)g)[tid];
    float4 bv = ((const float4*)bb)[tid];
    float4 o;
    o.x = (v.x - mu) * rstd * gv.x + bv.x;
    o.y = (v.y - mu) * rstd * gv.y + bv.y;
    o.z = (v.z - mu) * rstd * gv.z + bv.z;
    o.w = (v.w - mu) * rstd * gv.w + bv.w;
    ((float4*)(xn + row * DIMM))[tid] = o;
}

// ---------------- null kv fill ----------------
__global__ __launch_bounds__(256) void nullkv_kernel(const float* __restrict__ nkv,
                                                     float* __restrict__ kT,
                                                     float* __restrict__ vv) {
    int tid = blockIdx.x * 256 + threadIdx.x;
    if (tid >= NHEAD * 2 * DHEAD) return;
    int d = tid & 63, p = (tid >> 6) & 1, h = tid >> 7;
    kT[(h * DHEAD + d) * JPAD + p] = nkv[((0 * NHEAD + h) * 2 + p) * DHEAD + d];
    vv[(h * VSTR + p) * DHEAD + d] = nkv[((1 * NHEAD + h) * 2 + p) * DHEAD + d];
}

// ============ QKV GEMM: 128x64 tile, 8x4 micro, split-K=2 ============
// grid (8, 24, 2); writes partials P[z][1024][1536]
__global__ __launch_bounds__(256, 4) void qkv_gemm_part(const float* __restrict__ A,
                                                        const float* __restrict__ B,
                                                        float* __restrict__ P) {
    const int K = 512, Nn = 1536, KH = 256;
    __shared__ float As[16][128];
    __shared__ float Bs[16][64];
    int tid = threadIdx.x;
    int m0 = blockIdx.x * 128, n0 = blockIdx.y * 64, kb = blockIdx.z * KH;
    int ty = tid >> 4, tx = tid & 15;      // ty 0..15, tx 0..15
    float acc[8][4] = {};
    for (int k0 = 0; k0 < KH; k0 += 16) {
        // A: 128 rows x 16 k = 512 float4, 2 per thread (transposed store)
#pragma unroll
        for (int u = 0; u < 2; ++u) {
            int idx = tid * 2 + u;
            int row = idx >> 2, kq = (idx & 3) << 2;
            float4 av = *(const float4*)(A + (size_t)(m0 + row) * K + kb + k0 + kq);
            As[kq + 0][row] = av.x; As[kq + 1][row] = av.y;
            As[kq + 2][row] = av.z; As[kq + 3][row] = av.w;
        }
        // B: 16 k x 64 n = 256 float4... 1 per thread
        {
            int krow = tid >> 4, n4 = (tid & 15) << 2;
            *(float4*)&Bs[krow][n4] = *(const float4*)(B + (size_t)(kb + k0 + krow) * Nn + n0 + n4);
        }
        __syncthreads();
#pragma unroll
        for (int kk = 0; kk < 16; ++kk) {
            float a8[8], b4[4];
#pragma unroll
            for (int u = 0; u < 4; ++u) a8[u] = As[kk][ty * 4 + u];
#pragma unroll
            for (int u = 0; u < 4; ++u) a8[4 + u] = As[kk][64 + ty * 4 + u];
#pragma unroll
            for (int u = 0; u < 4; ++u) b4[u] = Bs[kk][tx * 4 + u];
#pragma unroll
            for (int r = 0; r < 8; ++r)
#pragma unroll
                for (int c = 0; c < 4; ++c)
                    acc[r][c] = fmaf(a8[r], b4[c], acc[r][c]);
        }
        __syncthreads();
    }
    float* Pz = P + (size_t)blockIdx.z * 1024 * 1536;
#pragma unroll
    for (int r = 0; r < 8; ++r) {
        int m = m0 + ((r >> 2) << 6) + ty * 4 + (r & 3);
        float4 ov = {acc[r][0], acc[r][1], acc[r][2], acc[r][3]};
        *(float4*)(Pz + (size_t)m * 1536 + n0 + tx * 4) = ov;
    }
}

// scatter P0+P1 -> q (scaled), kT, vv.  grid (6, 1024)
__global__ __launch_bounds__(256) void qkv_scatter(const float* __restrict__ P0,
                                                   const float* __restrict__ P1,
                                                   float* __restrict__ qo,
                                                   float* __restrict__ kT,
                                                   float* __restrict__ vo) {
    int c = blockIdx.x * 256 + threadIdx.x;
    int m = blockIdx.y;
    size_t idx = (size_t)m * 1536 + c;
    float val = P0[idx] + P1[idx];
    if (c < 512) {
        int h = c >> 6, d = c & 63;
        qo[((h << 10) + m) * 64 + d] = val * 0.125f;
    } else if (c < 1024) {
        int c2 = c - 512, h = c2 >> 6, d = c2 & 63;
        kT[(h * 64 + d) * JPAD + 2 + m] = val;
    } else {
        int c2 = c - 1024, h = c2 >> 6, d = c2 & 63;
        vo[(h * VSTR + 2 + m) * DHEAD + d] = val;
    }
}

// ============ monolithic fallback QKV GEMM ============
__global__ __launch_bounds__(256) void qkv_gemm_mono(const float* __restrict__ A,
                                                     const float* __restrict__ B,
                                                     float* __restrict__ qo,
                                                     float* __restrict__ kT,
                                                     float* __restrict__ vo) {
    const int K = 512, Nn = 1536;
    __shared__ float As[16][64];
    __shared__ float Bs[16][64];
    int tid = threadIdx.x;
    int m0 = blockIdx.x * 64, n0 = blockIdx.y * 64;
    int ty = tid >> 4, tx = tid & 15;
    int lam = tid >> 2, lak = (tid & 3) << 2;
    int lbk = tid >> 4, lbn = (tid & 15) << 2;
    float acc[4][4] = {};
    for (int k0 = 0; k0 < K; k0 += 16) {
        float4 av = *(const float4*)(A + (m0 + lam) * K + k0 + lak);
        float4 bv = *(const float4*)(B + (size_t)(k0 + lbk) * Nn + n0 + lbn);
        As[lak + 0][lam] = av.x; As[lak + 1][lam] = av.y;
        As[lak + 2][lam] = av.z; As[lak + 3][lam] = av.w;
        *(float4*)&Bs[lbk][lbn] = bv;
        __syncthreads();
#pragma unroll
        for (int kk = 0; kk < 16; ++kk) {
            float a4[4], b4[4];
#pragma unroll
            for (int u = 0; u < 4; ++u) a4[u] = As[kk][ty * 4 + u];
#pragma unroll
            for (int u = 0; u < 4; ++u) b4[u] = Bs[kk][tx * 4 + u];
#pragma unroll
            for (int ii = 0; ii < 4; ++ii)
#pragma unroll
                for (int jj = 0; jj < 4; ++jj)
                    acc[ii][jj] = fmaf(a4[ii], b4[jj], acc[ii][jj]);
        }
        __syncthreads();
    }
#pragma unroll
    for (int ii = 0; ii < 4; ++ii) {
        int m = m0 + ty * 4 + ii;
#pragma unroll
        for (int jj = 0; jj < 4; ++jj) {
            int c = n0 + tx * 4 + jj;
            float val = acc[ii][jj];
            if (c < 512) {
                int h = c >> 6, d = c & 63;
                qo[((h << 10) + m) * 64 + d] = val * 0.125f;
            } else if (c < 1024) {
                int c2 = c - 512, h = c2 >> 6, d = c2 & 63;
                kT[(h * 64 + d) * JPAD + 2 + m] = val;
            } else {
                int c2 = c - 1024, h = c2 >> 6, d = c2 & 63;
                vo[(h * VSTR + 2 + m) * DHEAD + d] = val;
            }
        }
    }
}

// ---------------- sim + CD (no PV), 1 wave/block, DPP reductions ----------------
// grid 4096; writes final p rows (padded to PROW, zeros beyond) to pbuf.
__global__ __launch_bounds__(64, 4) void cd_kernel64(const float* __restrict__ q,
                                                     const float* __restrict__ kT,
                                                     float* __restrict__ pbuf) {
    __shared__ float qA[64], qB[64];
    int lane = threadIdx.x;
    int p = blockIdx.x;
    int h = p >> 9, ip = p & 511;
    int iA = 1023 - ip, iB = ip;
    int nvA = iA + 3, nvB = iB + 3;

    qA[lane] = q[(((h << 10) + iA) << 6) + lane];
    qB[lane] = q[(((h << 10) + iB) << 6) + lane];
    // single wave: LDS write->read ordered by lgkmcnt, no barrier needed

    // ---- scores: lane owns j = 4*lane + c + 256*t ----
    const float* kbase = kT + (size_t)(h << 6) * JPAD + (lane << 2);
    float4 sA[5] = {}; float4 sB[3] = {};
    for (int d4 = 0; d4 < 64; d4 += 4) {
        float4 qa4 = *(const float4*)&qA[d4];
        float4 qb4 = *(const float4*)&qB[d4];
#pragma unroll
        for (int dd = 0; dd < 4; ++dd) {
            float qa = ((const float*)&qa4)[dd];
            float qb = ((const float*)&qb4)[dd];
            const float* kd = kbase + (size_t)(d4 + dd) * JPAD;
            float4 kv[5];
#pragma unroll
            for (int t = 0; t < 5; ++t) kv[t] = *(const float4*)(kd + (t << 8));
#pragma unroll
            for (int t = 0; t < 5; ++t) {
                sA[t].x = fmaf(qa, kv[t].x, sA[t].x);
                sA[t].y = fmaf(qa, kv[t].y, sA[t].y);
                sA[t].z = fmaf(qa, kv[t].z, sA[t].z);
                sA[t].w = fmaf(qa, kv[t].w, sA[t].w);
            }
#pragma unroll
            for (int t = 0; t < 3; ++t) {
                sB[t].x = fmaf(qb, kv[t].x, sB[t].x);
                sB[t].y = fmaf(qb, kv[t].y, sB[t].y);
                sB[t].z = fmaf(qb, kv[t].z, sB[t].z);
                sB[t].w = fmaf(qb, kv[t].w, sB[t].w);
            }
        }
    }

    // ---- mask (x10), row maxes ----
    int jb = lane << 2;
    float mA = -INFINITY, mB = -INFINITY;
#pragma unroll
    for (int t = 0; t < 5; ++t) {
        float* sp = (float*)&sA[t];
#pragma unroll
        for (int c = 0; c < 4; ++c) {
            int j = jb + c + (t << 8);
            float v = (j < nvA) ? sp[c] * 10.f : -INFINITY;
            sp[c] = v; mA = fmaxf(mA, v);
        }
    }
#pragma unroll
    for (int t = 0; t < 3; ++t) {
        float* sp = (float*)&sB[t];
#pragma unroll
        for (int c = 0; c < 4; ++c) {
            int j = jb + c + (t << 8);
            float v = (j < nvB) ? sp[c] * 10.f : -INFINITY;
            sp[c] = v; mB = fmaxf(mB, v);
        }
    }
    mA = dpp_max64(mA); mB = dpp_max64(mB);

    // ---- E tables ----
    float4 EA[5], E2A[5], EB[3], E2B[3];
#pragma unroll
    for (int t = 0; t < 5; ++t) {
        float* sp = (float*)&sA[t]; float* ep = (float*)&EA[t]; float* e2p = (float*)&E2A[t];
#pragma unroll
        for (int c = 0; c < 4; ++c) { float e = __expf(sp[c] - mA); ep[c] = e; e2p[c] = e * e; }
    }
#pragma unroll
    for (int t = 0; t < 3; ++t) {
        float* sp = (float*)&sB[t]; float* ep = (float*)&EB[t]; float* e2p = (float*)&E2B[t];
#pragma unroll
        for (int c = 0; c < 4; ++c) { float e = __expf(sp[c] - mB); ep[c] = e; e2p[c] = e * e; }
    }

    // ---- CD loop ----
    float gA = LOGK - __logf((float)nvA) + mA;
    float gB = LOGK - __logf((float)nvB) + mB;
#pragma unroll 1
    for (int it = 1; it < 50; ++it) {
        float egA = __expf(fminf(gA, 80.f));
        float egB = __expf(fminf(gB, 80.f));
        float a0 = 0.f, a1 = 0.f, a2 = 0.f, a3 = 0.f;
        float b0 = 0.f, b1 = 0.f, b2 = 0.f, b3 = 0.f;
#pragma unroll
        for (int t = 0; t < 5; ++t) {
            a0 += fminf(((float*)&EA[t])[0], ((float*)&E2A[t])[0] * egA);
            a1 += fminf(((float*)&EA[t])[1], ((float*)&E2A[t])[1] * egA);
            a2 += fminf(((float*)&EA[t])[2], ((float*)&E2A[t])[2] * egA);
            a3 += fminf(((float*)&EA[t])[3], ((float*)&E2A[t])[3] * egA);
        }
#pragma unroll
        for (int t = 0; t < 3; ++t) {
            b0 += fminf(((float*)&EB[t])[0], ((float*)&E2B[t])[0] * egB);
            b1 += fminf(((float*)&EB[t])[1], ((float*)&E2B[t])[1] * egB);
            b2 += fminf(((float*)&EB[t])[2], ((float*)&E2B[t])[2] * egB);
            b3 += fminf(((float*)&EB[t])[3], ((float*)&E2B[t])[3] * egB);
        }
        float sumA = dpp_sum64((a0 + a1) + (a2 + a3));
        float sumB = dpp_sum64((b0 + b1) + (b2 + b3));
        float gA2 = LOGK - __logf(sumA);
        float gB2 = LOGK - __logf(sumB);
        bool conv = (__float_as_int(gA2) == __float_as_int(gA)) &&
                    (__float_as_int(gB2) == __float_as_int(gB));
        gA = gA2; gB = gB2;
        if (conv) break;
    }

    // ---- final p -> pbuf rows (zeros in masked/padded area) ----
    float egA = __expf(fminf(gA, 80.f));
    float egB = __expf(fminf(gB, 80.f));
    float* rowA = pbuf + (size_t)((h << 10) + iA) * PROW;
    float* rowB = pbuf + (size_t)((h << 10) + iB) * PROW;
#pragma unroll
    for (int t = 0; t < 5; ++t) {
        float4 pv;
        float w;
        w = ((float*)&EA[t])[0] * egA; pv.x = w * fminf(1.f, w);
        w = ((float*)&EA[t])[1] * egA; pv.y = w * fminf(1.f, w);
        w = ((float*)&EA[t])[2] * egA; pv.z = w * fminf(1.f, w);
        w = ((float*)&EA[t])[3] * egA; pv.w = w * fminf(1.f, w);
        int j0 = jb + (t << 8);
        if (j0 < PROW) *(float4*)(rowA + j0) = pv;
    }
#pragma unroll
    for (int t = 0; t < 3; ++t) {
        float4 pv;
        float w;
        w = ((float*)&EB[t])[0] * egB; pv.x = w * fminf(1.f, w);
        w = ((float*)&EB[t])[1] * egB; pv.y = w * fminf(1.f, w);
        w = ((float*)&EB[t])[2] * egB; pv.z = w * fminf(1.f, w);
        w = ((float*)&EB[t])[3] * egB; pv.w = w * fminf(1.f, w);
        *(float4*)(rowB + jb + (t << 8)) = pv;
    }
    float4 z4 = {0.f, 0.f, 0.f, 0.f};
#pragma unroll
    for (int t = 3; t < 5; ++t) {
        int j0 = jb + (t << 8);
        if (j0 < PROW) *(float4*)(rowB + j0) = z4;
    }
}

// ---------------- PV GEMM: ao[i][h*64+d] = p[i][:] @ v[:][d] ----------------
// grid (16, 8, 2): 64-row tile, head, j-half (528 each). partials Pv[z][1024][512]
__global__ __launch_bounds__(256) void pv_gemm(const float* __restrict__ pbuf,
                                               const float* __restrict__ vv,
                                               float* __restrict__ Pv) {
    __shared__ float As[16][64];
    __shared__ float Bs[16][64];
    int tid = threadIdx.x;
    int i0 = blockIdx.x * 64, h = blockIdx.y, z = blockIdx.z;
    int jbase = z * 528;
    int ty = tid >> 4, tx = tid & 15;
    int lam = tid >> 2, lak = (tid & 3) << 2;
    int lbk = tid >> 4, lbn = (tid & 15) << 2;
    const float* Ab = pbuf + (size_t)((h << 10) + i0) * PROW + jbase;
    const float* Bb = vv + ((size_t)h * VSTR + jbase) * DHEAD;
    float acc[4][4] = {};
    for (int k0 = 0; k0 < 528; k0 += 16) {
        float4 av = *(const float4*)(Ab + (size_t)lam * PROW + k0 + lak);
        float4 bv = *(const float4*)(Bb + (size_t)(k0 + lbk) * DHEAD + lbn);
        As[lak + 0][lam] = av.x; As[lak + 1][lam] = av.y;
        As[lak + 2][lam] = av.z; As[lak + 3][lam] = av.w;
        *(float4*)&Bs[lbk][lbn] = bv;
        __syncthreads();
#pragma unroll
        for (int kk = 0; kk < 16; ++kk) {
            float a4[4], b4[4];
#pragma unroll
            for (int u = 0; u < 4; ++u) a4[u] = As[kk][ty * 4 + u];
#pragma unroll
            for (int u = 0; u < 4; ++u) b4[u] = Bs[kk][tx * 4 + u];
#pragma unroll
            for (int ii = 0; ii < 4; ++ii)
#pragma unroll
                for (int jj = 0; jj < 4; ++jj)
                    acc[ii][jj] = fmaf(a4[ii], b4[jj], acc[ii][jj]);
        }
        __syncthreads();
    }
    float* Pz = Pv + (size_t)z * 1024 * 512;
#pragma unroll
    for (int ii = 0; ii < 4; ++ii) {
        int i = i0 + ty * 4 + ii;
        float4 ov = {acc[ii][0], acc[ii][1], acc[ii][2], acc[ii][3]};
        *(float4*)(Pz + ((size_t)i << 9) + (h << 6) + tx * 4) = ov;
    }
}

// ============ out GEMM (A = Pv0+Pv1 fused), split-K=2 ============
__global__ __launch_bounds__(256) void out_gemm_fused(const float* __restrict__ A0,
                                                      const float* __restrict__ A1,
                                                      const float* __restrict__ B,
                                                      float* __restrict__ Po) {
    const int K = 512, Nn = 512, KH = 256;
    __shared__ float As[16][64];
    __shared__ float Bs[16][64];
    int tid = threadIdx.x;
    int m0 = blockIdx.x * 64, n0 = blockIdx.y * 64, kb = blockIdx.z * KH;
    int ty = tid >> 4, tx = tid & 15;
    int lam = tid >> 2, lak = (tid & 3) << 2;
    int lbk = tid >> 4, lbn = (tid & 15) << 2;
    float acc[4][4] = {};
    for (int k0 = 0; k0 < KH; k0 += 16) {
        size_t aidx = (size_t)(m0 + lam) * K + kb + k0 + lak;
        float4 a0 = *(const float4*)(A0 + aidx);
        float4 a1 = *(const float4*)(A1 + aidx);
        float4 av = {a0.x + a1.x, a0.y + a1.y, a0.z + a1.z, a0.w + a1.w};
        float4 bv = *(const float4*)(B + (size_t)(kb + k0 + lbk) * Nn + n0 + lbn);
        As[lak + 0][lam] = av.x; As[lak + 1][lam] = av.y;
        As[lak + 2][lam] = av.z; As[lak + 3][lam] = av.w;
        *(float4*)&Bs[lbk][lbn] = bv;
        __syncthreads();
#pragma unroll
        for (int kk = 0; kk < 16; ++kk) {
            float a4[4], b4[4];
#pragma unroll
            for (int u = 0; u < 4; ++u) a4[u] = As[kk][ty * 4 + u];
#pragma unroll
            for (int u = 0; u < 4; ++u) b4[u] = Bs[kk][tx * 4 + u];
#pragma unroll
            for (int ii = 0; ii < 4; ++ii)
#pragma unroll
                for (int jj = 0; jj < 4; ++jj)
                    acc[ii][jj] = fmaf(a4[ii], b4[jj], acc[ii][jj]);
        }
        __syncthreads();
    }
    float* Pz = Po + (size_t)blockIdx.z * 1024 * 512;
#pragma unroll
    for (int ii = 0; ii < 4; ++ii) {
        int m = m0 + ty * 4 + ii;
#pragma unroll
        for (int jj = 0; jj < 4; ++jj)
            Pz[(size_t)m * 512 + n0 + tx * 4 + jj] = acc[ii][jj];
    }
}

__global__ __launch_bounds__(256) void out_combine(const float* __restrict__ P0,
                                                   const float* __restrict__ P1,
                                                   float* __restrict__ C) {
    int g = blockIdx.x * 256 + threadIdx.x;
    C[g] = P0[g] + P1[g];
}

// ============ fallback: round-4 fused CD (in-kernel PV), ao out ============
__global__ __launch_bounds__(256, 4) void cd_pair_kernel(const float* __restrict__ q,
                                                         const float* __restrict__ kT,
                                                         const float* __restrict__ vv,
                                                         float* __restrict__ ao) {
    __shared__ float qs[4][2][64];
    __shared__ float psA[4][1280];
    __shared__ float psB[4][768];
    int wave = threadIdx.x >> 6, lane = threadIdx.x & 63;
    int p = (blockIdx.x << 2) + wave;
    int h = p >> 9, ip = p & 511;
    int iA = 1023 - ip, iB = ip;
    int nvA = iA + 3, nvB = iB + 3;

    qs[wave][0][lane] = q[(((h << 10) + iA) << 6) + lane];
    qs[wave][1][lane] = q[(((h << 10) + iB) << 6) + lane];

    const float* kbase = kT + (size_t)(h << 6) * JPAD + (lane << 2);
    float4 sA[5] = {}; float4 sB[3] = {};
    for (int d4 = 0; d4 < 64; d4 += 4) {
        float4 qa4 = *(const float4*)&qs[wave][0][d4];
        float4 qb4 = *(const float4*)&qs[wave][1][d4];
#pragma unroll
        for (int dd = 0; dd < 4; ++dd) {
            float qa = ((const float*)&qa4)[dd];
            float qb = ((const float*)&qb4)[dd];
            const float* kd = kbase + (size_t)(d4 + dd) * JPAD;
            float4 kv[5];
#pragma unroll
            for (int t = 0; t < 5; ++t) kv[t] = *(const float4*)(kd + (t << 8));
#pragma unroll
            for (int t = 0; t < 5; ++t) {
                sA[t].x = fmaf(qa, kv[t].x, sA[t].x);
                sA[t].y = fmaf(qa, kv[t].y, sA[t].y);
                sA[t].z = fmaf(qa, kv[t].z, sA[t].z);
                sA[t].w = fmaf(qa, kv[t].w, sA[t].w);
            }
#pragma unroll
            for (int t = 0; t < 3; ++t) {
                sB[t].x = fmaf(qb, kv[t].x, sB[t].x);
                sB[t].y = fmaf(qb, kv[t].y, sB[t].y);
                sB[t].z = fmaf(qb, kv[t].z, sB[t].z);
                sB[t].w = fmaf(qb, kv[t].w, sB[t].w);
            }
        }
    }
    int jb = lane << 2;
    float mA = -INFINITY, mB = -INFINITY;
#pragma unroll
    for (int t = 0; t < 5; ++t) {
        float* sp = (float*)&sA[t];
#pragma unroll
        for (int c = 0; c < 4; ++c) {
            int j = jb + c + (t << 8);
            float v = (j < nvA) ? sp[c] * 10.f : -INFINITY;
            sp[c] = v; mA = fmaxf(mA, v);
        }
    }
#pragma unroll
    for (int t = 0; t < 3; ++t) {
        float* sp = (float*)&sB[t];
#pragma unroll
        for (int c = 0; c < 4; ++c) {
            int j = jb + c + (t << 8);
            float v = (j < nvB) ? sp[c] * 10.f : -INFINITY;
            sp[c] = v; mB = fmaxf(mB, v);
        }
    }
    mA = wave_max64(mA); mB = wave_max64(mB);
    float4 EA[5], E2A[5], EB[3], E2B[3];
#pragma unroll
    for (int t = 0; t < 5; ++t) {
        float* sp = (float*)&sA[t]; float* ep = (float*)&EA[t]; float* e2p = (float*)&E2A[t];
#pragma unroll
        for (int c = 0; c < 4; ++c) { float e = __expf(sp[c] - mA); ep[c] = e; e2p[c] = e * e; }
    }
#pragma unroll
    for (int t = 0; t < 3; ++t) {
        float* sp = (float*)&sB[t]; float* ep = (float*)&EB[t]; float* e2p = (float*)&E2B[t];
#pragma unroll
        for (int c = 0; c < 4; ++c) { float e = __expf(sp[c] - mB); ep[c] = e; e2p[c] = e * e; }
    }
    float gA = LOGK - __logf((float)nvA) + mA;
    float gB = LOGK - __logf((float)nvB) + mB;
#pragma unroll 1
    for (int it = 1; it < 50; ++it) {
        float egA = __expf(fminf(gA, 80.f));
        float egB = __expf(fminf(gB, 80.f));
        float4 aA = {0.f, 0.f, 0.f, 0.f}, aB = {0.f, 0.f, 0.f, 0.f};
#pragma unroll
        for (int t = 0; t < 5; ++t) {
            aA.x += fminf(((float*)&EA[t])[0], ((float*)&E2A[t])[0] * egA);
            aA.y += fminf(((float*)&EA[t])[1], ((float*)&E2A[t])[1] * egA);
            aA.z += fminf(((float*)&EA[t])[2], ((float*)&E2A[t])[2] * egA);
            aA.w += fminf(((float*)&EA[t])[3], ((float*)&E2A[t])[3] * egA);
        }
#pragma unroll
        for (int t = 0; t < 3; ++t) {
            aB.x += fminf(((float*)&EB[t])[0], ((float*)&E2B[t])[0] * egB);
            aB.y += fminf(((float*)&EB[t])[1], ((float*)&E2B[t])[1] * egB);
            aB.z += fminf(((float*)&EB[t])[2], ((float*)&E2B[t])[2] * egB);
            aB.w += fminf(((float*)&EB[t])[3], ((float*)&E2B[t])[3] * egB);
        }
        float sumA = wave_sum64((aA.x + aA.y) + (aA.z + aA.w));
        float sumB = wave_sum64((aB.x + aB.y) + (aB.z + aB.w));
        float gA2 = LOGK - __logf(sumA);
        float gB2 = LOGK - __logf(sumB);
        bool conv = (__float_as_int(gA2) == __float_as_int(gA)) &&
                    (__float_as_int(gB2) == __float_as_int(gB));
        gA = gA2; gB = gB2;
        if (conv) break;
    }
    {
        float egA = __expf(fminf(gA, 80.f));
        float egB = __expf(fminf(gB, 80.f));
#pragma unroll
        for (int t = 0; t < 5; ++t) {
            float4 pv;
            pv.x = ((float*)&EA[t])[0] * egA; pv.x = pv.x * fminf(1.f, pv.x);
            pv.y = ((float*)&EA[t])[1] * egA; pv.y = pv.y * fminf(1.f, pv.y);
            pv.z = ((float*)&EA[t])[2] * egA; pv.z = pv.z * fminf(1.f, pv.z);
            pv.w = ((float*)&EA[t])[3] * egA; pv.w = pv.w * fminf(1.f, pv.w);
            *(float4*)&psA[wave][jb + (t << 8)] = pv;
        }
#pragma unroll
        for (int t = 0; t < 3; ++t) {
            float4 pv;
            pv.x = ((float*)&EB[t])[0] * egB; pv.x = pv.x * fminf(1.f, pv.x);
            pv.y = ((float*)&EB[t])[1] * egB; pv.y = pv.y * fminf(1.f, pv.y);
            pv.z = ((float*)&EB[t])[2] * egB; pv.z = pv.z * fminf(1.f, pv.z);
            pv.w = ((float*)&EB[t])[3] * egB; pv.w = pv.w * fminf(1.f, pv.w);
            *(float4*)&psB[wave][jb + (t << 8)] = pv;
        }
    }
    const float* vb = vv + (size_t)h * VSTR * DHEAD + lane;
    float oA0 = 0.f, oA1 = 0.f, oB0 = 0.f, oB1 = 0.f;
    int nB4 = (nvB + 3) & ~3;
    int nA4 = (nvA + 3) & ~3;
    int j = 0;
    for (; j < nB4; j += 4) {
        float4 pa = *(const float4*)&psA[wave][j];
        float4 pb = *(const float4*)&psB[wave][j];
        float v0 = vb[(size_t)(j + 0) * 64];
        float v1 = vb[(size_t)(j + 1) * 64];
        float v2 = vb[(size_t)(j + 2) * 64];
        float v3 = vb[(size_t)(j + 3) * 64];
        oA0 = fmaf(pa.x, v0, oA0); oA1 = fmaf(pa.y, v1, oA1);
        oA0 = fmaf(pa.z, v2, oA0); oA1 = fmaf(pa.w, v3, oA1);
        oB0 = fmaf(pb.x, v0, oB0); oB1 = fmaf(pb.y, v1, oB1);
        oB0 = fmaf(pb.z, v2, oB0); oB1 = fmaf(pb.w, v3, oB1);
    }
    for (; j < nA4; j += 4) {
        float4 pa = *(const float4*)&psA[wave][j];
        float v0 = vb[(size_t)(j + 0) * 64];
        float v1 = vb[(size_t)(j + 1) * 64];
        float v2 = vb[(size_t)(j + 2) * 64];
        float v3 = vb[(size_t)(j + 3) * 64];
        oA0 = fmaf(pa.x, v0, oA0); oA1 = fmaf(pa.y, v1, oA1);
        oA0 = fmaf(pa.z, v2, oA0); oA1 = fmaf(pa.w, v3, oA1);
    }
    ao[(iA << 9) + (h << 6) + lane] = oA0 + oA1;
    ao[(iB << 9) + (h << 6) + lane] = oB0 + oB1;
}

__global__ __launch_bounds__(256) void out_gemm_mono(const float* __restrict__ A,
                                                     const float* __restrict__ B,
                                                     float* __restrict__ C) {
    const int K = 512, Nn = 512;
    __shared__ float As[16][64];
    __shared__ float Bs[16][64];
    int tid = threadIdx.x;
    int m0 = blockIdx.x * 64, n0 = blockIdx.y * 64;
    int ty = tid >> 4, tx = tid & 15;
    int lam = tid >> 2, lak = (tid & 3) << 2;
    int lbk = tid >> 4, lbn = (tid & 15) << 2;
    float acc[4][4] = {};
    for (int k0 = 0; k0 < K; k0 += 16) {
        float4 av = *(const float4*)(A + (m0 + lam) * K + k0 + lak);
        float4 bv = *(const float4*)(B + (size_t)(k0 + lbk) * Nn + n0 + lbn);
        As[lak + 0][lam] = av.x; As[lak + 1][lam] = av.y;
        As[lak + 2][lam] = av.z; As[lak + 3][lam] = av.w;
        *(float4*)&Bs[lbk][lbn] = bv;
        __syncthreads();
#pragma unroll
        for (int kk = 0; kk < 16; ++kk) {
            float a4[4], b4[4];
#pragma unroll
            for (int u = 0; u < 4; ++u) a4[u] = As[kk][ty * 4 + u];
#pragma unroll
            for (int u = 0; u < 4; ++u) b4[u] = Bs[kk][tx * 4 + u];
#pragma unroll
            for (int ii = 0; ii < 4; ++ii)
#pragma unroll
                for (int jj = 0; jj < 4; ++jj)
                    acc[ii][jj] = fmaf(a4[ii], b4[jj], acc[ii][jj]);
        }
        __syncthreads();
    }
#pragma unroll
    for (int ii = 0; ii < 4; ++ii) {
        int m = m0 + ty * 4 + ii;
#pragma unroll
        for (int jj = 0; jj < 4; ++jj)
            C[(size_t)m * Nn + n0 + tx * 4 + jj] = acc[ii][jj];
    }
}

extern "C" void kernel_launch(void* const* d_in, const int* in_sizes, int n_in,
                              void* d_out, int out_size, void* d_ws, size_t ws_size,
                              hipStream_t stream) {
    const float* x      = (const float*)d_in[0];
    const float* w_qkv  = (const float*)d_in[1];
    const float* w_out  = (const float*)d_in[2];
    const float* nullkv = (const float*)d_in[3];
    const float* ln_g   = (const float*)d_in[4];
    const float* ln_b   = (const float*)d_in[5];
    float* ws = (float*)d_ws;
    float* out = (float*)d_out;

    const size_t XN   = 1024 * 512;
    const size_t QSZ  = 1024 * 512;
    const size_t KTSZ = (size_t)NHEAD * 64 * JPAD;
    const size_t VVSZ = (size_t)NHEAD * VSTR * 64;
    const size_t PSZ  = (size_t)1024 * 1536;
    const size_t PBSZ = (size_t)8192 * PROW;
    const size_t PVSZ = (size_t)1024 * 512;

    float* xn = ws;
    float* q  = xn + XN;
    float* kT = q + QSZ;
    float* vv = kT + KTSZ;

    const size_t needPrimary = (XN + QSZ + KTSZ + VVSZ + 2 * PSZ + PBSZ + 2 * PVSZ) * 4;

    hipLaunchKernelGGL(ln_kernel, dim3(1024), dim3(128), 0, stream, x, ln_g, ln_b, xn);
    hipLaunchKernelGGL(nullkv_kernel, dim3(4), dim3(256), 0, stream, nullkv, kT, vv);

    if (ws_size >= needPrimary) {
        float* P0   = vv + VVSZ;
        float* P1   = P0 + PSZ;
        float* pbuf = P1 + PSZ;
        float* Pv0  = pbuf + PBSZ;
        float* Pv1  = Pv0 + PVSZ;
        float* Po0  = xn;   // xn dead after qkv_gemm_part
        float* Po1  = q;    // q dead after cd_kernel64
        hipLaunchKernelGGL(qkv_gemm_part, dim3(8, 24, 2), dim3(256), 0, stream, xn, w_qkv, P0);
        hipLaunchKernelGGL(qkv_scatter, dim3(6, 1024), dim3(256), 0, stream, P0, P1, q, kT, vv);
        hipLaunchKernelGGL(cd_kernel64, dim3(4096), dim3(64), 0, stream, q, kT, pbuf);
        hipLaunchKernelGGL(pv_gemm, dim3(16, 8, 2), dim3(256), 0, stream, pbuf, vv, Pv0);
        hipLaunchKernelGGL(out_gemm_fused, dim3(16, 8, 2), dim3(256), 0, stream, Pv0, Pv1, w_out, Po0);
        hipLaunchKernelGGL(out_combine, dim3(2048), dim3(256), 0, stream, Po0, Po1, out);
    } else {
        float* ao = vv + VVSZ;
        hipLaunchKernelGGL(qkv_gemm_mono, dim3(16, 24), dim3(256), 0, stream, xn, w_qkv, q, kT, vv);
        hipLaunchKernelGGL(cd_pair_kernel, dim3(1024), dim3(256), 0, stream, q, kT, vv, ao);
        hipLaunchKernelGGL(out_gemm_mono, dim3(16, 8), dim3(256), 0, stream, ao, w_out, out);
    }
}

// Round 6
// 215.951 us; speedup vs baseline: 5.3236x; 1.0692x over previous
//
#include <hip/hip_runtime.h>
#include <math.h>

#define NTOK 1024
#define DIMM 512
#define NHEAD 8
#define DHEAD 64
#define JTOT 1026      // NTOK + 2 null kv
#define JPAD 1088      // 17*64 padded kT row
#define VSTR 1056      // v rows per head (padded)
#define PROW 1056      // pbuf row stride (floats)
#define LOGK 2.0794415416798357f

typedef __bf16 bf16x8 __attribute__((ext_vector_type(8)));
typedef float  f32x4  __attribute__((ext_vector_type(4)));

// ---------------- DPP wave reductions (64 lanes), result broadcast ----------------
__device__ __forceinline__ float dpp_sum64(float x) {
    int v;
    v = __builtin_amdgcn_update_dpp(0, __float_as_int(x), 0x111, 0xf, 0xf, true); x += __int_as_float(v);
    v = __builtin_amdgcn_update_dpp(0, __float_as_int(x), 0x112, 0xf, 0xf, true); x += __int_as_float(v);
    v = __builtin_amdgcn_update_dpp(0, __float_as_int(x), 0x114, 0xf, 0xf, true); x += __int_as_float(v);
    v = __builtin_amdgcn_update_dpp(0, __float_as_int(x), 0x118, 0xf, 0xf, true); x += __int_as_float(v);
    v = __builtin_amdgcn_update_dpp(0, __float_as_int(x), 0x142, 0xa, 0xf, true); x += __int_as_float(v);
    v = __builtin_amdgcn_update_dpp(0, __float_as_int(x), 0x143, 0xc, 0xf, true); x += __int_as_float(v);
    return __int_as_float(__builtin_amdgcn_readlane(__float_as_int(x), 63));
}
__device__ __forceinline__ float dpp_max64(float x) {
    int v;
    v = __builtin_amdgcn_update_dpp(__float_as_int(x), __float_as_int(x), 0x111, 0xf, 0xf, false); x = fmaxf(x, __int_as_float(v));
    v = __builtin_amdgcn_update_dpp(__float_as_int(x), __float_as_int(x), 0x112, 0xf, 0xf, false); x = fmaxf(x, __int_as_float(v));
    v = __builtin_amdgcn_update_dpp(__float_as_int(x), __float_as_int(x), 0x114, 0xf, 0xf, false); x = fmaxf(x, __int_as_float(v));
    v = __builtin_amdgcn_update_dpp(__float_as_int(x), __float_as_int(x), 0x118, 0xf, 0xf, false); x = fmaxf(x, __int_as_float(v));
    v = __builtin_amdgcn_update_dpp(__float_as_int(x), __float_as_int(x), 0x142, 0xa, 0xf, false); x = fmaxf(x, __int_as_float(v));
    v = __builtin_amdgcn_update_dpp(__float_as_int(x), __float_as_int(x), 0x143, 0xc, 0xf, false); x = fmaxf(x, __int_as_float(v));
    return __int_as_float(__builtin_amdgcn_readlane(__float_as_int(x), 63));
}

// ---------------- LayerNorm ----------------
__global__ __launch_bounds__(128) void ln_kernel(const float* __restrict__ x,
                                                 const float* __restrict__ g,
                                                 const float* __restrict__ bb,
                                                 float* __restrict__ xn) {
    int row = blockIdx.x, tid = threadIdx.x;
    float4 v = ((const float4*)(x + row * DIMM))[tid];
    float s  = v.x + v.y + v.z + v.w;
    float ss = fmaf(v.x, v.x, fmaf(v.y, v.y, fmaf(v.z, v.z, v.w * v.w)));
#pragma unroll
    for (int off = 32; off; off >>= 1) {
        s  += __shfl_down(s, off);
        ss += __shfl_down(ss, off);
    }
    __shared__ float sm[4];
    if ((tid & 63) == 0) { sm[(tid >> 6) * 2] = s; sm[(tid >> 6) * 2 + 1] = ss; }
    __syncthreads();
    s = sm[0] + sm[2]; ss = sm[1] + sm[3];
    float mu   = s * (1.f / DIMM);
    float var  = ss * (1.f / DIMM) - mu * mu;
    float rstd = 1.f / sqrtf(var + 1e-5f);
    float4 gv = ((const float4*)g)[tid];
    float4 bv = ((const float4*)bb)[tid];
    float4 o;
    o.x = (v.x - mu) * rstd * gv.x + bv.x;
    o.y = (v.y - mu) * rstd * gv.y + bv.y;
    o.z = (v.z - mu) * rstd * gv.z + bv.z;
    o.w = (v.w - mu) * rstd * gv.w + bv.w;
    ((float4*)(xn + row * DIMM))[tid] = o;
}

// ---------------- null kv fill ----------------
__global__ __launch_bounds__(256) void nullkv_kernel(const float* __restrict__ nkv,
                                                     float* __restrict__ kT,
                                                     float* __restrict__ vv) {
    int tid = blockIdx.x * 256 + threadIdx.x;
    if (tid >= NHEAD * 2 * DHEAD) return;
    int d = tid & 63, p = (tid >> 6) & 1, h = tid >> 7;
    kT[(h * DHEAD + d) * JPAD + p] = nkv[((0 * NHEAD + h) * 2 + p) * DHEAD + d];
    vv[(h * VSTR + p) * DHEAD + d] = nkv[((1 * NHEAD + h) * 2 + p) * DHEAD + d];
}

// ============ QKV GEMM: split-bf16 3-pass MFMA, 64x64 tile ============
// C = xn[1024x512] @ w_qkv[512x1536], fp32-class accuracy via Ah*Bh+Al*Bh+Ah*Bl.
// grid (16, 24), 256 threads (4 waves, 16-row stripes).
__global__ __launch_bounds__(256, 2) void qkv_mfma(const float* __restrict__ A,
                                                   const float* __restrict__ B,
                                                   float* __restrict__ qo,
                                                   float* __restrict__ kT,
                                                   float* __restrict__ vo) {
    __shared__ __bf16 Ah[64][40], Al[64][40];   // [row][k], pad stride 40
    __shared__ __bf16 Bh[64][40], Bl[64][40];   // transposed: [n][k]
    int tid = threadIdx.x;
    int m0 = blockIdx.x * 64, n0 = blockIdx.y * 64;
    int l = tid & 63, w = tid >> 6;
    f32x4 acc[4] = {};

    for (int k0 = 0; k0 < 512; k0 += 32) {
        // stage A (64x32): 512 float4, 2 per thread
#pragma unroll
        for (int u = 0; u < 2; ++u) {
            int idx = tid + (u << 8);
            int row = idx >> 3, kq = (idx & 7) << 2;
            float4 av = *(const float4*)(A + (size_t)(m0 + row) * 512 + k0 + kq);
#pragma unroll
            for (int e = 0; e < 4; ++e) {
                float a = ((const float*)&av)[e];
                __bf16 hi = (__bf16)a;
                __bf16 lo = (__bf16)(a - (float)hi);
                Ah[row][kq + e] = hi;
                Al[row][kq + e] = lo;
            }
        }
        // stage B (32x64) transposed: 512 float4, 2 per thread
#pragma unroll
        for (int u = 0; u < 2; ++u) {
            int idx = tid + (u << 8);
            int krow = idx >> 4, nc = (idx & 15) << 2;
            float4 bv = *(const float4*)(B + (size_t)(k0 + krow) * 1536 + n0 + nc);
#pragma unroll
            for (int e = 0; e < 4; ++e) {
                float b = ((const float*)&bv)[e];
                __bf16 hi = (__bf16)b;
                __bf16 lo = (__bf16)(b - (float)hi);
                Bh[nc + e][krow] = hi;
                Bl[nc + e][krow] = lo;
            }
        }
        __syncthreads();
        int arow = (w << 4) + (l & 15);
        int koff = (l >> 4) << 3;
        bf16x8 ah = *(const bf16x8*)&Ah[arow][koff];
        bf16x8 al = *(const bf16x8*)&Al[arow][koff];
#pragma unroll
        for (int nt = 0; nt < 4; ++nt) {
            int bcol = (nt << 4) + (l & 15);
            bf16x8 bh = *(const bf16x8*)&Bh[bcol][koff];
            bf16x8 bl = *(const bf16x8*)&Bl[bcol][koff];
            acc[nt] = __builtin_amdgcn_mfma_f32_16x16x32_bf16(ah, bh, acc[nt], 0, 0, 0);
            acc[nt] = __builtin_amdgcn_mfma_f32_16x16x32_bf16(al, bh, acc[nt], 0, 0, 0);
            acc[nt] = __builtin_amdgcn_mfma_f32_16x16x32_bf16(ah, bl, acc[nt], 0, 0, 0);
        }
        __syncthreads();
    }
    // epilogue: D row = (l>>4)*4+j, col = l&15 (m89-verified); scatter to q/kT/v
#pragma unroll
    for (int nt = 0; nt < 4; ++nt) {
        int c = n0 + (nt << 4) + (l & 15);
#pragma unroll
        for (int j = 0; j < 4; ++j) {
            int m = m0 + (w << 4) + ((l >> 4) << 2) + j;
            float val = acc[nt][j];
            if (c < 512) {
                int h = c >> 6, d = c & 63;
                qo[(((h << 10) + m) << 6) + d] = val * 0.125f;
            } else if (c < 1024) {
                int c2 = c - 512, h = c2 >> 6, d = c2 & 63;
                kT[(h * 64 + d) * JPAD + 2 + m] = val;
            } else {
                int c2 = c - 1024, h = c2 >> 6, d = c2 & 63;
                vo[(h * VSTR + 2 + m) * DHEAD + d] = val;
            }
        }
    }
}

// ---------------- sim + CD (no PV), 1 wave/block, DPP reductions ----------------
// (unchanged from round 5: proven 84 us)
__global__ __launch_bounds__(64, 4) void cd_kernel64(const float* __restrict__ q,
                                                     const float* __restrict__ kT,
                                                     float* __restrict__ pbuf) {
    __shared__ float qA[64], qB[64];
    int lane = threadIdx.x;
    int p = blockIdx.x;
    int h = p >> 9, ip = p & 511;
    int iA = 1023 - ip, iB = ip;
    int nvA = iA + 3, nvB = iB + 3;

    qA[lane] = q[(((h << 10) + iA) << 6) + lane];
    qB[lane] = q[(((h << 10) + iB) << 6) + lane];

    const float* kbase = kT + (size_t)(h << 6) * JPAD + (lane << 2);
    float4 sA[5] = {}; float4 sB[3] = {};
    for (int d4 = 0; d4 < 64; d4 += 4) {
        float4 qa4 = *(const float4*)&qA[d4];
        float4 qb4 = *(const float4*)&qB[d4];
#pragma unroll
        for (int dd = 0; dd < 4; ++dd) {
            float qa = ((const float*)&qa4)[dd];
            float qb = ((const float*)&qb4)[dd];
            const float* kd = kbase + (size_t)(d4 + dd) * JPAD;
            float4 kv[5];
#pragma unroll
            for (int t = 0; t < 5; ++t) kv[t] = *(const float4*)(kd + (t << 8));
#pragma unroll
            for (int t = 0; t < 5; ++t) {
                sA[t].x = fmaf(qa, kv[t].x, sA[t].x);
                sA[t].y = fmaf(qa, kv[t].y, sA[t].y);
                sA[t].z = fmaf(qa, kv[t].z, sA[t].z);
                sA[t].w = fmaf(qa, kv[t].w, sA[t].w);
            }
#pragma unroll
            for (int t = 0; t < 3; ++t) {
                sB[t].x = fmaf(qb, kv[t].x, sB[t].x);
                sB[t].y = fmaf(qb, kv[t].y, sB[t].y);
                sB[t].z = fmaf(qb, kv[t].z, sB[t].z);
                sB[t].w = fmaf(qb, kv[t].w, sB[t].w);
            }
        }
    }

    int jb = lane << 2;
    float mA = -INFINITY, mB = -INFINITY;
#pragma unroll
    for (int t = 0; t < 5; ++t) {
        float* sp = (float*)&sA[t];
#pragma unroll
        for (int c = 0; c < 4; ++c) {
            int j = jb + c + (t << 8);
            float v = (j < nvA) ? sp[c] * 10.f : -INFINITY;
            sp[c] = v; mA = fmaxf(mA, v);
        }
    }
#pragma unroll
    for (int t = 0; t < 3; ++t) {
        float* sp = (float*)&sB[t];
#pragma unroll
        for (int c = 0; c < 4; ++c) {
            int j = jb + c + (t << 8);
            float v = (j < nvB) ? sp[c] * 10.f : -INFINITY;
            sp[c] = v; mB = fmaxf(mB, v);
        }
    }
    mA = dpp_max64(mA); mB = dpp_max64(mB);

    float4 EA[5], E2A[5], EB[3], E2B[3];
#pragma unroll
    for (int t = 0; t < 5; ++t) {
        float* sp = (float*)&sA[t]; float* ep = (float*)&EA[t]; float* e2p = (float*)&E2A[t];
#pragma unroll
        for (int c = 0; c < 4; ++c) { float e = __expf(sp[c] - mA); ep[c] = e; e2p[c] = e * e; }
    }
#pragma unroll
    for (int t = 0; t < 3; ++t) {
        float* sp = (float*)&sB[t]; float* ep = (float*)&EB[t]; float* e2p = (float*)&E2B[t];
#pragma unroll
        for (int c = 0; c < 4; ++c) { float e = __expf(sp[c] - mB); ep[c] = e; e2p[c] = e * e; }
    }

    float gA = LOGK - __logf((float)nvA) + mA;
    float gB = LOGK - __logf((float)nvB) + mB;
#pragma unroll 1
    for (int it = 1; it < 50; ++it) {
        float egA = __expf(fminf(gA, 80.f));
        float egB = __expf(fminf(gB, 80.f));
        float a0 = 0.f, a1 = 0.f, a2 = 0.f, a3 = 0.f;
        float b0 = 0.f, b1 = 0.f, b2 = 0.f, b3 = 0.f;
#pragma unroll
        for (int t = 0; t < 5; ++t) {
            a0 += fminf(((float*)&EA[t])[0], ((float*)&E2A[t])[0] * egA);
            a1 += fminf(((float*)&EA[t])[1], ((float*)&E2A[t])[1] * egA);
            a2 += fminf(((float*)&EA[t])[2], ((float*)&E2A[t])[2] * egA);
            a3 += fminf(((float*)&EA[t])[3], ((float*)&E2A[t])[3] * egA);
        }
#pragma unroll
        for (int t = 0; t < 3; ++t) {
            b0 += fminf(((float*)&EB[t])[0], ((float*)&E2B[t])[0] * egB);
            b1 += fminf(((float*)&EB[t])[1], ((float*)&E2B[t])[1] * egB);
            b2 += fminf(((float*)&EB[t])[2], ((float*)&E2B[t])[2] * egB);
            b3 += fminf(((float*)&EB[t])[3], ((float*)&E2B[t])[3] * egB);
        }
        float sumA = dpp_sum64((a0 + a1) + (a2 + a3));
        float sumB = dpp_sum64((b0 + b1) + (b2 + b3));
        float gA2 = LOGK - __logf(sumA);
        float gB2 = LOGK - __logf(sumB);
        bool conv = (__float_as_int(gA2) == __float_as_int(gA)) &&
                    (__float_as_int(gB2) == __float_as_int(gB));
        gA = gA2; gB = gB2;
        if (conv) break;
    }

    float egA = __expf(fminf(gA, 80.f));
    float egB = __expf(fminf(gB, 80.f));
    float* rowA = pbuf + (size_t)((h << 10) + iA) * PROW;
    float* rowB = pbuf + (size_t)((h << 10) + iB) * PROW;
#pragma unroll
    for (int t = 0; t < 5; ++t) {
        float4 pv;
        float w;
        w = ((float*)&EA[t])[0] * egA; pv.x = w * fminf(1.f, w);
        w = ((float*)&EA[t])[1] * egA; pv.y = w * fminf(1.f, w);
        w = ((float*)&EA[t])[2] * egA; pv.z = w * fminf(1.f, w);
        w = ((float*)&EA[t])[3] * egA; pv.w = w * fminf(1.f, w);
        int j0 = jb + (t << 8);
        if (j0 < PROW) *(float4*)(rowA + j0) = pv;
    }
#pragma unroll
    for (int t = 0; t < 3; ++t) {
        float4 pv;
        float w;
        w = ((float*)&EB[t])[0] * egB; pv.x = w * fminf(1.f, w);
        w = ((float*)&EB[t])[1] * egB; pv.y = w * fminf(1.f, w);
        w = ((float*)&EB[t])[2] * egB; pv.z = w * fminf(1.f, w);
        w = ((float*)&EB[t])[3] * egB; pv.w = w * fminf(1.f, w);
        *(float4*)(rowB + jb + (t << 8)) = pv;
    }
    float4 z4 = {0.f, 0.f, 0.f, 0.f};
#pragma unroll
    for (int t = 3; t < 5; ++t) {
        int j0 = jb + (t << 8);
        if (j0 < PROW) *(float4*)(rowB + j0) = z4;
    }
}

// ============ PV GEMM: bf16 MFMA, 32x64 tile, K=1056 ============
// ao[i][h*64+d] = p[h,i,:] @ v[h,:,d].  grid (32, 8), 256 threads.
__global__ __launch_bounds__(256, 2) void pv_mfma(const float* __restrict__ pbuf,
                                                  const float* __restrict__ vv,
                                                  float* __restrict__ ao) {
    __shared__ __bf16 Ap[32][40];   // [i][k]
    __shared__ __bf16 Bv[64][40];   // transposed: [d][k]
    int tid = threadIdx.x;
    int i0 = blockIdx.x * 32, h = blockIdx.y;
    int l = tid & 63, w = tid >> 6;
    int rt = w & 1, ch = w >> 1;
    f32x4 acc[2] = {};
    const float* Ab = pbuf + (size_t)((h << 10) + i0) * PROW;
    const float* Bb = vv + (size_t)h * VSTR * DHEAD;

    for (int k0 = 0; k0 < 1056; k0 += 32) {
        {   // A: 32x32 = 256 float4, 1 per thread
            int row = tid >> 3, kq = (tid & 7) << 2;
            float4 av = *(const float4*)(Ab + (size_t)row * PROW + k0 + kq);
#pragma unroll
            for (int e = 0; e < 4; ++e) Ap[row][kq + e] = (__bf16)((const float*)&av)[e];
        }
        // B: 32 j-rows x 64 d = 512 float4, 2 per thread (transpose)
#pragma unroll
        for (int u = 0; u < 2; ++u) {
            int idx = tid + (u << 8);
            int krow = idx >> 4, dc = (idx & 15) << 2;
            float4 bv = *(const float4*)(Bb + (size_t)(k0 + krow) * 64 + dc);
#pragma unroll
            for (int e = 0; e < 4; ++e) Bv[dc + e][krow] = (__bf16)((const float*)&bv)[e];
        }
        __syncthreads();
        int arow = (rt << 4) + (l & 15);
        int koff = (l >> 4) << 3;
        bf16x8 af = *(const bf16x8*)&Ap[arow][koff];
#pragma unroll
        for (int nt = 0; nt < 2; ++nt) {
            int bcol = (ch << 5) + (nt << 4) + (l & 15);
            bf16x8 bf = *(const bf16x8*)&Bv[bcol][koff];
            acc[nt] = __builtin_amdgcn_mfma_f32_16x16x32_bf16(af, bf, acc[nt], 0, 0, 0);
        }
        __syncthreads();
    }
#pragma unroll
    for (int nt = 0; nt < 2; ++nt) {
#pragma unroll
        for (int j = 0; j < 4; ++j) {
            int i = i0 + (rt << 4) + ((l >> 4) << 2) + j;
            int d = (ch << 5) + (nt << 4) + (l & 15);
            ao[((size_t)i << 9) + (h << 6) + d] = acc[nt][j];
        }
    }
}

// ============ out GEMM: bf16 MFMA, 32x64 tile, K=512 ============
// out = ao[1024x512] @ w_out[512x512].  grid (32, 8), 256 threads.
__global__ __launch_bounds__(256, 2) void out_mfma(const float* __restrict__ A,
                                                   const float* __restrict__ B,
                                                   float* __restrict__ C) {
    __shared__ __bf16 Aa[32][40];
    __shared__ __bf16 Bw[64][40];   // transposed: [n][k]
    int tid = threadIdx.x;
    int m0 = blockIdx.x * 32, n0 = blockIdx.y * 64;
    int l = tid & 63, w = tid >> 6;
    int rt = w & 1, ch = w >> 1;
    f32x4 acc[2] = {};

    for (int k0 = 0; k0 < 512; k0 += 32) {
        {   // A: 32x32 = 256 float4, 1 per thread
            int row = tid >> 3, kq = (tid & 7) << 2;
            float4 av = *(const float4*)(A + (size_t)(m0 + row) * 512 + k0 + kq);
#pragma unroll
            for (int e = 0; e < 4; ++e) Aa[row][kq + e] = (__bf16)((const float*)&av)[e];
        }
#pragma unroll
        for (int u = 0; u < 2; ++u) {
            int idx = tid + (u << 8);
            int krow = idx >> 4, nc = (idx & 15) << 2;
            float4 bv = *(const float4*)(B + (size_t)(k0 + krow) * 512 + n0 + nc);
#pragma unroll
            for (int e = 0; e < 4; ++e) Bw[nc + e][krow] = (__bf16)((const float*)&bv)[e];
        }
        __syncthreads();
        int arow = (rt << 4) + (l & 15);
        int koff = (l >> 4) << 3;
        bf16x8 af = *(const bf16x8*)&Aa[arow][koff];
#pragma unroll
        for (int nt = 0; nt < 2; ++nt) {
            int bcol = (ch << 5) + (nt << 4) + (l & 15);
            bf16x8 bf = *(const bf16x8*)&Bw[bcol][koff];
            acc[nt] = __builtin_amdgcn_mfma_f32_16x16x32_bf16(af, bf, acc[nt], 0, 0, 0);
        }
        __syncthreads();
    }
#pragma unroll
    for (int nt = 0; nt < 2; ++nt) {
#pragma unroll
        for (int j = 0; j < 4; ++j) {
            int m = m0 + (rt << 4) + ((l >> 4) << 2) + j;
            int c = n0 + (ch << 5) + (nt << 4) + (l & 15);
            C[(size_t)m * 512 + c] = acc[nt][j];
        }
    }
}

extern "C" void kernel_launch(void* const* d_in, const int* in_sizes, int n_in,
                              void* d_out, int out_size, void* d_ws, size_t ws_size,
                              hipStream_t stream) {
    const float* x      = (const float*)d_in[0];
    const float* w_qkv  = (const float*)d_in[1];
    const float* w_out  = (const float*)d_in[2];
    const float* nullkv = (const float*)d_in[3];
    const float* ln_g   = (const float*)d_in[4];
    const float* ln_b   = (const float*)d_in[5];
    float* ws = (float*)d_ws;
    float* out = (float*)d_out;

    const size_t XN   = 1024 * 512;
    const size_t QSZ  = 1024 * 512;
    const size_t KTSZ = (size_t)NHEAD * 64 * JPAD;
    const size_t VVSZ = (size_t)NHEAD * VSTR * 64;
    const size_t PBSZ = (size_t)8192 * PROW;

    float* xn   = ws;
    float* q    = xn + XN;
    float* kT   = q + QSZ;
    float* vv   = kT + KTSZ;
    float* pbuf = vv + VVSZ;
    float* ao   = pbuf + PBSZ;

    hipLaunchKernelGGL(ln_kernel, dim3(1024), dim3(128), 0, stream, x, ln_g, ln_b, xn);
    hipLaunchKernelGGL(nullkv_kernel, dim3(4), dim3(256), 0, stream, nullkv, kT, vv);
    hipLaunchKernelGGL(qkv_mfma, dim3(16, 24), dim3(256), 0, stream, xn, w_qkv, q, kT, vv);
    hipLaunchKernelGGL(cd_kernel64, dim3(4096), dim3(64), 0, stream, q, kT, pbuf);
    hipLaunchKernelGGL(pv_mfma, dim3(32, 8), dim3(256), 0, stream, pbuf, vv, ao);
    hipLaunchKernelGGL(out_mfma, dim3(32, 8), dim3(256), 0, stream, ao, w_out, out);
}

// Round 8
// 180.725 us; speedup vs baseline: 6.3612x; 1.1949x over previous
//
#include <hip/hip_runtime.h>
#include <math.h>

#define NHEAD 8
#define SROW 1088          // s row stride (fp32)
#define PBF  2176          // bf16 slots per s row (aliased p storage)
#define VSTR 1056          // vT row length (bf16)
#define LOGK 2.0794415416798357f

typedef __bf16 bf16x8 __attribute__((ext_vector_type(8)));
typedef __bf16 bf16x4 __attribute__((ext_vector_type(4)));
typedef float  f32x4  __attribute__((ext_vector_type(4)));

__device__ __forceinline__ void split2(float v, __bf16& hi, __bf16& lo) {
    hi = (__bf16)v; lo = (__bf16)(v - (float)hi);
}

// ---------------- DPP wave reductions (64 lanes), result broadcast ----------------
__device__ __forceinline__ float dpp_sum64(float x) {
    int v;
    v = __builtin_amdgcn_update_dpp(0, __float_as_int(x), 0x111, 0xf, 0xf, true); x += __int_as_float(v);
    v = __builtin_amdgcn_update_dpp(0, __float_as_int(x), 0x112, 0xf, 0xf, true); x += __int_as_float(v);
    v = __builtin_amdgcn_update_dpp(0, __float_as_int(x), 0x114, 0xf, 0xf, true); x += __int_as_float(v);
    v = __builtin_amdgcn_update_dpp(0, __float_as_int(x), 0x118, 0xf, 0xf, true); x += __int_as_float(v);
    v = __builtin_amdgcn_update_dpp(0, __float_as_int(x), 0x142, 0xa, 0xf, true); x += __int_as_float(v);
    v = __builtin_amdgcn_update_dpp(0, __float_as_int(x), 0x143, 0xc, 0xf, true); x += __int_as_float(v);
    return __int_as_float(__builtin_amdgcn_readlane(__float_as_int(x), 63));
}
__device__ __forceinline__ float dpp_max64(float x) {
    int v;
    v = __builtin_amdgcn_update_dpp(__float_as_int(x), __float_as_int(x), 0x111, 0xf, 0xf, false); x = fmaxf(x, __int_as_float(v));
    v = __builtin_amdgcn_update_dpp(__float_as_int(x), __float_as_int(x), 0x112, 0xf, 0xf, false); x = fmaxf(x, __int_as_float(v));
    v = __builtin_amdgcn_update_dpp(__float_as_int(x), __float_as_int(x), 0x114, 0xf, 0xf, false); x = fmaxf(x, __int_as_float(v));
    v = __builtin_amdgcn_update_dpp(__float_as_int(x), __float_as_int(x), 0x118, 0xf, 0xf, false); x = fmaxf(x, __int_as_float(v));
    v = __builtin_amdgcn_update_dpp(__float_as_int(x), __float_as_int(x), 0x142, 0xa, 0xf, false); x = fmaxf(x, __int_as_float(v));
    v = __builtin_amdgcn_update_dpp(__float_as_int(x), __float_as_int(x), 0x143, 0xc, 0xf, false); x = fmaxf(x, __int_as_float(v));
    return __int_as_float(__builtin_amdgcn_readlane(__float_as_int(x), 63));
}

// ---------------- LayerNorm -> split bf16 (hi/lo) ----------------
__global__ __launch_bounds__(128) void ln_split(const float* __restrict__ x,
                                                const float* __restrict__ g,
                                                const float* __restrict__ bb,
                                                __bf16* __restrict__ xnh,
                                                __bf16* __restrict__ xnl) {
    int row = blockIdx.x, tid = threadIdx.x;
    float4 v = ((const float4*)(x + row * 512))[tid];
    float s  = v.x + v.y + v.z + v.w;
    float ss = fmaf(v.x, v.x, fmaf(v.y, v.y, fmaf(v.z, v.z, v.w * v.w)));
#pragma unroll
    for (int off = 32; off; off >>= 1) {
        s  += __shfl_down(s, off);
        ss += __shfl_down(ss, off);
    }
    __shared__ float sm[4];
    if ((tid & 63) == 0) { sm[(tid >> 6) * 2] = s; sm[(tid >> 6) * 2 + 1] = ss; }
    __syncthreads();
    s = sm[0] + sm[2]; ss = sm[1] + sm[3];
    float mu   = s * (1.f / 512);
    float var  = ss * (1.f / 512) - mu * mu;
    float rstd = 1.f / sqrtf(var + 1e-5f);
    float4 gv = ((const float4*)g)[tid];
    float4 bv = ((const float4*)bb)[tid];
    float o[4];
    o[0] = (v.x - mu) * rstd * gv.x + bv.x;
    o[1] = (v.y - mu) * rstd * gv.y + bv.y;
    o[2] = (v.z - mu) * rstd * gv.z + bv.z;
    o[3] = (v.w - mu) * rstd * gv.w + bv.w;
    bf16x4 h4, l4;
#pragma unroll
    for (int e = 0; e < 4; ++e) { __bf16 hi, lo; split2(o[e], hi, lo); h4[e] = hi; l4[e] = lo; }
    *(bf16x4*)(xnh + (size_t)row * 512 + tid * 4) = h4;
    *(bf16x4*)(xnl + (size_t)row * 512 + tid * 4) = l4;
}

// ---------------- w_qkv [512k][1536n] -> transposed split bf16 [n][k] ----------------
__global__ __launch_bounds__(256) void wsplit_qkv(const float* __restrict__ B,
                                                  __bf16* __restrict__ bh,
                                                  __bf16* __restrict__ bl) {
    __shared__ float T[64][65];
    int k0 = blockIdx.x * 64, n0 = blockIdx.y * 64, tid = threadIdx.x;
    int r = tid >> 2, c0 = (tid & 3) << 4;
#pragma unroll
    for (int u = 0; u < 4; ++u) {
        float4 w = *(const float4*)(B + (size_t)(k0 + r) * 1536 + n0 + c0 + 4 * u);
        T[r][c0 + 4 * u + 0] = w.x; T[r][c0 + 4 * u + 1] = w.y;
        T[r][c0 + 4 * u + 2] = w.z; T[r][c0 + 4 * u + 3] = w.w;
    }
    __syncthreads();
    int nr = tid >> 2, kc0 = (tid & 3) << 4;
#pragma unroll
    for (int u = 0; u < 4; ++u) {
        bf16x4 h4, l4;
#pragma unroll
        for (int e = 0; e < 4; ++e) {
            __bf16 hi, lo; split2(T[kc0 + 4 * u + e][nr], hi, lo);
            h4[e] = hi; l4[e] = lo;
        }
        *(bf16x4*)(bh + (size_t)(n0 + nr) * 512 + k0 + kc0 + 4 * u) = h4;
        *(bf16x4*)(bl + (size_t)(n0 + nr) * 512 + k0 + kc0 + 4 * u) = l4;
    }
}

// ---------------- w_out [512][512] -> transposed bf16 [n][k] ----------------
__global__ __launch_bounds__(256) void wsplit_out(const float* __restrict__ B,
                                                  __bf16* __restrict__ wo) {
    __shared__ float T[64][65];
    int k0 = blockIdx.x * 64, n0 = blockIdx.y * 64, tid = threadIdx.x;
    int r = tid >> 2, c0 = (tid & 3) << 4;
#pragma unroll
    for (int u = 0; u < 4; ++u) {
        float4 w = *(const float4*)(B + (size_t)(k0 + r) * 512 + n0 + c0 + 4 * u);
        T[r][c0 + 4 * u + 0] = w.x; T[r][c0 + 4 * u + 1] = w.y;
        T[r][c0 + 4 * u + 2] = w.z; T[r][c0 + 4 * u + 3] = w.w;
    }
    __syncthreads();
    int nr = tid >> 2, kc0 = (tid & 3) << 4;
#pragma unroll
    for (int u = 0; u < 4; ++u) {
        bf16x4 h4;
#pragma unroll
        for (int e = 0; e < 4; ++e) h4[e] = (__bf16)T[kc0 + 4 * u + e][nr];
        *(bf16x4*)(wo + (size_t)(n0 + nr) * 512 + k0 + kc0 + 4 * u) = h4;
    }
}

// ---------------- null kv -> kh/kl rows 0,1; vT cols 0,1; zero vT tail ----------------
__global__ __launch_bounds__(256) void nullkv2(const float* __restrict__ nkv,
                                               __bf16* __restrict__ kh,
                                               __bf16* __restrict__ kl,
                                               __bf16* __restrict__ vT) {
    int tid = blockIdx.x * 256 + threadIdx.x;   // 1024 total
    int d = tid & 63, p = (tid >> 6) & 1, h = tid >> 7;
    float kvf = nkv[((0 * NHEAD + h) * 2 + p) * 64 + d];
    __bf16 hi, lo; split2(kvf, hi, lo);
    kh[((size_t)h * SROW + p) * 64 + d] = hi;
    kl[((size_t)h * SROW + p) * 64 + d] = lo;
    float vf = nkv[((NHEAD + h) * 2 + p) * 64 + d];
    vT[((size_t)(h * 64) + d) * VSTR + p] = (__bf16)vf;
    // zero vT j in [1026,1056): 8*64*30 = 15360 = 1024*15
    int base = tid * 15;
#pragma unroll
    for (int e = 0; e < 15; ++e) {
        int z = base + e;
        int jj = 1026 + (z % 30);
        int hd = z / 30;
        vT[(size_t)hd * VSTR + jj] = (__bf16)0.f;
    }
}

// ============ QKV GEMM: LDS-free 3-pass MFMA ============
// xn(split) @ wqkv(split,[n][k]) -> q(x1.25, split), k(split), vT(bf16)
// grid (32, 24): tile 32m x 64n, 4 waves (2 m-stripes x 2 n-halves)
__global__ __launch_bounds__(256, 2) void qkv_mfma(const __bf16* __restrict__ xh,
                                                   const __bf16* __restrict__ xl,
                                                   const __bf16* __restrict__ bh,
                                                   const __bf16* __restrict__ bl,
                                                   __bf16* __restrict__ qh,
                                                   __bf16* __restrict__ ql,
                                                   __bf16* __restrict__ kh,
                                                   __bf16* __restrict__ kl,
                                                   __bf16* __restrict__ vT) {
    int tid = threadIdx.x, l = tid & 63, w = tid >> 6;
    int m0 = blockIdx.x * 32, n0 = blockIdx.y * 64;
    int ms = (w & 1) << 4, nh2 = (w >> 1) << 5;
    int arow = m0 + ms + (l & 15);
    f32x4 acc[2] = {};
    for (int ks = 0; ks < 16; ++ks) {
        int koff = ((l >> 4) << 3) + (ks << 5);
        bf16x8 ah = *(const bf16x8*)(xh + (size_t)arow * 512 + koff);
        bf16x8 al = *(const bf16x8*)(xl + (size_t)arow * 512 + koff);
#pragma unroll
        for (int ct = 0; ct < 2; ++ct) {
            int ncol = n0 + nh2 + (ct << 4) + (l & 15);
            bf16x8 bhv = *(const bf16x8*)(bh + (size_t)ncol * 512 + koff);
            bf16x8 blv = *(const bf16x8*)(bl + (size_t)ncol * 512 + koff);
            acc[ct] = __builtin_amdgcn_mfma_f32_16x16x32_bf16(ah, bhv, acc[ct], 0, 0, 0);
            acc[ct] = __builtin_amdgcn_mfma_f32_16x16x32_bf16(al, bhv, acc[ct], 0, 0, 0);
            acc[ct] = __builtin_amdgcn_mfma_f32_16x16x32_bf16(ah, blv, acc[ct], 0, 0, 0);
        }
    }
#pragma unroll
    for (int ct = 0; ct < 2; ++ct) {
        int c = n0 + nh2 + (ct << 4) + (l & 15);
#pragma unroll
        for (int r = 0; r < 4; ++r) {
            int m = m0 + ms + ((l >> 4) << 2) + r;
            float val = acc[ct][r];
            if (c < 512) {
                int h = c >> 6, d = c & 63;
                __bf16 hi, lo; split2(val * 1.25f, hi, lo);   // 0.125 scale * 10 (1/eps)
                qh[(((size_t)(h << 10)) + m) * 64 + d] = hi;
                ql[(((size_t)(h << 10)) + m) * 64 + d] = lo;
            } else if (c < 1024) {
                int c2 = c - 512, h = c2 >> 6, d = c2 & 63;
                __bf16 hi, lo; split2(val, hi, lo);
                kh[((size_t)h * SROW + 2 + m) * 64 + d] = hi;
                kl[((size_t)h * SROW + 2 + m) * 64 + d] = lo;
            } else {
                int c2 = c - 1024, h = c2 >> 6, d = c2 & 63;
                vT[((size_t)(h * 64) + d) * VSTR + 2 + m] = (__bf16)val;
            }
        }
    }
}

// ============ QK^T: LDS-free 3-pass MFMA, causal tiles only ============
// s[h][i][j] = 10 * q.k  (q pre-scaled). grid (152, 8): tile 64i x 64j, 4 waves by i-stripe.
__global__ __launch_bounds__(256, 2) void qk_mfma(const __bf16* __restrict__ qh,
                                                  const __bf16* __restrict__ ql,
                                                  const __bf16* __restrict__ kh,
                                                  const __bf16* __restrict__ kl,
                                                  float* __restrict__ s) {
    int b = blockIdx.x, h = blockIdx.y;
    int ti = (int)((-3.0f + sqrtf(9.0f + 8.0f * (float)b)) * 0.5f);
    while ((ti + 1) * (ti + 4) / 2 <= b) ++ti;
    while (ti * (ti + 3) / 2 > b) --ti;
    int tj = b - ti * (ti + 3) / 2;
    int i0 = ti << 6, j0 = tj << 6;

    int tid = threadIdx.x, l = tid & 63, w = tid >> 6;
    int arow = i0 + (w << 4) + (l & 15);
    const __bf16* qhb = qh + ((size_t)(h << 10) + arow) * 64;
    const __bf16* qlb = ql + ((size_t)(h << 10) + arow) * 64;
    f32x4 acc[4] = {};
#pragma unroll
    for (int ks = 0; ks < 2; ++ks) {
        int koff = ((l >> 4) << 3) + (ks << 5);
        bf16x8 ah = *(const bf16x8*)(qhb + koff);
        bf16x8 al = *(const bf16x8*)(qlb + koff);
#pragma unroll
        for (int ct = 0; ct < 4; ++ct) {
            int j = j0 + (ct << 4) + (l & 15);
            bf16x8 bhv = *(const bf16x8*)(kh + ((size_t)h * SROW + j) * 64 + koff);
            bf16x8 blv = *(const bf16x8*)(kl + ((size_t)h * SROW + j) * 64 + koff);
            acc[ct] = __builtin_amdgcn_mfma_f32_16x16x32_bf16(ah, bhv, acc[ct], 0, 0, 0);
            acc[ct] = __builtin_amdgcn_mfma_f32_16x16x32_bf16(al, bhv, acc[ct], 0, 0, 0);
            acc[ct] = __builtin_amdgcn_mfma_f32_16x16x32_bf16(ah, blv, acc[ct], 0, 0, 0);
        }
    }
#pragma unroll
    for (int ct = 0; ct < 4; ++ct) {
        int j = j0 + (ct << 4) + (l & 15);
#pragma unroll
        for (int r = 0; r < 4; ++r) {
            int i = i0 + (w << 4) + ((l >> 4) << 2) + r;
            s[((size_t)(h << 10) + i) * SROW + j] = acc[ct][r];
        }
    }
}

// ---------------- CD: load s rows, iterate, write p (bf16) in-place ----------------
// One wave per complementary pair (iA=1023-ip, iB=ip). Exact reference trajectory:
// analytic iter 1 + plain map with bitwise-converged freeze per row.
__global__ __launch_bounds__(64, 4) void cd_kernel(float* __restrict__ s) {
    int lane = threadIdx.x, p = blockIdx.x;
    int h = p >> 9, ip = p & 511;
    int iA = 1023 - ip, iB = ip;
    int nvA = iA + 3, nvB = iB + 3;
    float* rA = s + ((size_t)(h << 10) + iA) * SROW;
    float* rB = s + ((size_t)(h << 10) + iB) * SROW;
    int jb = lane << 2;

    float4 sA[5], sB[3];
#pragma unroll
    for (int t = 0; t < 5; ++t) {
        if (jb + (t << 8) < SROW) sA[t] = *(const float4*)(rA + jb + (t << 8));
        else { sA[t].x = sA[t].y = sA[t].z = sA[t].w = -INFINITY; }
    }
#pragma unroll
    for (int t = 0; t < 3; ++t) sB[t] = *(const float4*)(rB + jb + (t << 8));

    // mask + row max (s already x10)
    float mA = -INFINITY, mB = -INFINITY;
#pragma unroll
    for (int t = 0; t < 5; ++t) {
        float* sp = (float*)&sA[t];
#pragma unroll
        for (int c = 0; c < 4; ++c) {
            int j = jb + c + (t << 8);
            float v = (j < nvA) ? sp[c] : -INFINITY;
            sp[c] = v; mA = fmaxf(mA, v);
        }
    }
#pragma unroll
    for (int t = 0; t < 3; ++t) {
        float* sp = (float*)&sB[t];
#pragma unroll
        for (int c = 0; c < 4; ++c) {
            int j = jb + c + (t << 8);
            float v = (j < nvB) ? sp[c] : -INFINITY;
            sp[c] = v; mB = fmaxf(mB, v);
        }
    }
    mA = dpp_max64(mA); mB = dpp_max64(mB);

    float4 EA[5], E2A[5], EB[3], E2B[3];
#pragma unroll
    for (int t = 0; t < 5; ++t) {
        float* sp = (float*)&sA[t]; float* ep = (float*)&EA[t]; float* e2p = (float*)&E2A[t];
#pragma unroll
        for (int c = 0; c < 4; ++c) { float e = __expf(sp[c] - mA); ep[c] = e; e2p[c] = e * e; }
    }
#pragma unroll
    for (int t = 0; t < 3; ++t) {
        float* sp = (float*)&sB[t]; float* ep = (float*)&EB[t]; float* e2p = (float*)&E2B[t];
#pragma unroll
        for (int c = 0; c < 4; ++c) { float e = __expf(sp[c] - mB); ep[c] = e; e2p[c] = e * e; }
    }

    float gA = LOGK - __logf((float)nvA) + mA;
    float gB = LOGK - __logf((float)nvB) + mB;
    bool dA = false, dB = false;
#pragma unroll 1
    for (int it = 1; it < 50; ++it) {
        if (!dA) {
            float eg = __expf(fminf(gA, 80.f));
            float a0 = 0.f, a1 = 0.f, a2 = 0.f, a3 = 0.f;
#pragma unroll
            for (int t = 0; t < 5; ++t) {
                a0 += fminf(((float*)&EA[t])[0], ((float*)&E2A[t])[0] * eg);
                a1 += fminf(((float*)&EA[t])[1], ((float*)&E2A[t])[1] * eg);
                a2 += fminf(((float*)&EA[t])[2], ((float*)&E2A[t])[2] * eg);
                a3 += fminf(((float*)&EA[t])[3], ((float*)&E2A[t])[3] * eg);
            }
            float sum = dpp_sum64((a0 + a1) + (a2 + a3));
            float g2 = LOGK - __logf(sum);
            dA = (__float_as_int(g2) == __float_as_int(gA));
            gA = g2;
        }
        if (!dB) {
            float eg = __expf(fminf(gB, 80.f));
            float b0 = 0.f, b1 = 0.f, b2 = 0.f, b3 = 0.f;
#pragma unroll
            for (int t = 0; t < 3; ++t) {
                b0 += fminf(((float*)&EB[t])[0], ((float*)&E2B[t])[0] * eg);
                b1 += fminf(((float*)&EB[t])[1], ((float*)&E2B[t])[1] * eg);
                b2 += fminf(((float*)&EB[t])[2], ((float*)&E2B[t])[2] * eg);
                b3 += fminf(((float*)&EB[t])[3], ((float*)&E2B[t])[3] * eg);
            }
            float sum = dpp_sum64((b0 + b1) + (b2 + b3));
            float g2 = LOGK - __logf(sum);
            dB = (__float_as_int(g2) == __float_as_int(gB));
            gB = g2;
        }
        if (dA && dB) break;
    }

    // final p -> bf16, written over the s rows (fully read above)
    float egA = __expf(fminf(gA, 80.f));
    float egB = __expf(fminf(gB, 80.f));
    __bf16* pA = (__bf16*)rA;
    __bf16* pB = (__bf16*)rB;
#pragma unroll
    for (int t = 0; t < 5; ++t) {
        if (jb + (t << 8) < SROW) {
            bf16x4 pv;
#pragma unroll
            for (int c = 0; c < 4; ++c) {
                float wv = ((float*)&EA[t])[c] * egA;
                pv[c] = (__bf16)(wv * fminf(1.f, wv));
            }
            *(bf16x4*)(pA + jb + (t << 8)) = pv;
        }
    }
#pragma unroll
    for (int t = 0; t < 3; ++t) {
        bf16x4 pv;
#pragma unroll
        for (int c = 0; c < 4; ++c) {
            float wv = ((float*)&EB[t])[c] * egB;
            pv[c] = (__bf16)(wv * fminf(1.f, wv));
        }
        *(bf16x4*)(pB + jb + (t << 8)) = pv;
    }
    bf16x4 z4 = {};
#pragma unroll
    for (int t = 3; t < 5; ++t) {
        if (jb + (t << 8) < SROW) *(bf16x4*)(pB + jb + (t << 8)) = z4;
    }
}

// ============ PV: LDS-free bf16 MFMA. grid (64, 8): tile 16i x 64d, wave owns 16d ============
__global__ __launch_bounds__(256, 2) void pv_mfma(const float* __restrict__ s,
                                                  const __bf16* __restrict__ vT,
                                                  __bf16* __restrict__ ao) {
    int i0 = blockIdx.x << 4, h = blockIdx.y;
    int tid = threadIdx.x, l = tid & 63, w = tid >> 6;
    const __bf16* pbase = (const __bf16*)s;
    int arow = i0 + (l & 15);
    int dcol = (w << 4) + (l & 15);
    const __bf16* pr = pbase + ((size_t)(h << 10) + arow) * PBF;
    const __bf16* vr = vT + ((size_t)(h << 6) + dcol) * VSTR;
    f32x4 acc0 = {}, acc1 = {};
    int kb = (l >> 4) << 3;
#pragma unroll 4
    for (int ks = 0; ks < 32; ks += 2) {
        bf16x8 a0 = *(const bf16x8*)(pr + kb + (ks << 5));
        bf16x8 b0 = *(const bf16x8*)(vr + kb + (ks << 5));
        bf16x8 a1 = *(const bf16x8*)(pr + kb + ((ks + 1) << 5));
        bf16x8 b1 = *(const bf16x8*)(vr + kb + ((ks + 1) << 5));
        acc0 = __builtin_amdgcn_mfma_f32_16x16x32_bf16(a0, b0, acc0, 0, 0, 0);
        acc1 = __builtin_amdgcn_mfma_f32_16x16x32_bf16(a1, b1, acc1, 0, 0, 0);
    }
    {   // ks = 32 (k 1024..1055)
        bf16x8 a0 = *(const bf16x8*)(pr + kb + (32 << 5));
        bf16x8 b0 = *(const bf16x8*)(vr + kb + (32 << 5));
        acc0 = __builtin_amdgcn_mfma_f32_16x16x32_bf16(a0, b0, acc0, 0, 0, 0);
    }
#pragma unroll
    for (int r = 0; r < 4; ++r) {
        int i = i0 + ((l >> 4) << 2) + r;
        ao[(size_t)i * 512 + (h << 6) + dcol] = (__bf16)(acc0[r] + acc1[r]);
    }
}

// ============ OUT: LDS-free bf16 MFMA. grid (64, 8): tile 16m x 64n, wave owns 16n ============
__global__ __launch_bounds__(256, 2) void out_mfma(const __bf16* __restrict__ ao,
                                                   const __bf16* __restrict__ wo,
                                                   float* __restrict__ out) {
    int m0 = blockIdx.x << 4, bn = blockIdx.y;
    int tid = threadIdx.x, l = tid & 63, w = tid >> 6;
    int arow = m0 + (l & 15);
    int ncol = (bn << 6) + (w << 4) + (l & 15);
    const __bf16* ar = ao + (size_t)arow * 512;
    const __bf16* br = wo + (size_t)ncol * 512;
    f32x4 acc0 = {}, acc1 = {};
    int kb = (l >> 4) << 3;
#pragma unroll 4
    for (int ks = 0; ks < 16; ks += 2) {
        bf16x8 a0 = *(const bf16x8*)(ar + kb + (ks << 5));
        bf16x8 b0 = *(const bf16x8*)(br + kb + (ks << 5));
        bf16x8 a1 = *(const bf16x8*)(ar + kb + ((ks + 1) << 5));
        bf16x8 b1 = *(const bf16x8*)(br + kb + ((ks + 1) << 5));
        acc0 = __builtin_amdgcn_mfma_f32_16x16x32_bf16(a0, b0, acc0, 0, 0, 0);
        acc1 = __builtin_amdgcn_mfma_f32_16x16x32_bf16(a1, b1, acc1, 0, 0, 0);
    }
#pragma unroll
    for (int r = 0; r < 4; ++r) {
        int m = m0 + ((l >> 4) << 2) + r;
        out[(size_t)m * 512 + ncol] = acc0[r] + acc1[r];
    }
}

extern "C" void kernel_launch(void* const* d_in, const int* in_sizes, int n_in,
                              void* d_out, int out_size, void* d_ws, size_t ws_size,
                              hipStream_t stream) {
    const float* x      = (const float*)d_in[0];
    const float* w_qkv  = (const float*)d_in[1];
    const float* w_out  = (const float*)d_in[2];
    const float* nullkv = (const float*)d_in[3];
    const float* ln_g   = (const float*)d_in[4];
    const float* ln_b   = (const float*)d_in[5];
    float* ws = (float*)d_ws;
    float* out = (float*)d_out;

    // f32-slot offsets
    float* base = ws;
    __bf16* xnh = (__bf16*)(base);              base += 262144;   // 1024*512 bf16
    __bf16* xnl = (__bf16*)(base);              base += 262144;
    __bf16* wqh = (__bf16*)(base);              base += 393216;   // 1536*512 bf16
    __bf16* wql = (__bf16*)(base);              base += 393216;
    __bf16* qh  = (__bf16*)(base);              base += 262144;   // 8*1024*64
    __bf16* ql  = (__bf16*)(base);              base += 262144;
    __bf16* kh  = (__bf16*)(base);              base += 278528;   // 8*1088*64
    __bf16* kl  = (__bf16*)(base);              base += 278528;
    __bf16* vT  = (__bf16*)(base);              base += 270336;   // 8*64*1056
    __bf16* wo  = (__bf16*)(base);              base += 131072;   // 512*512
    __bf16* ao  = (__bf16*)(base);              base += 262144;   // 1024*512
    float*  s   = base;                                           // 8*1024*1088 fp32 (p aliased)

    hipLaunchKernelGGL(ln_split,   dim3(1024),    dim3(128), 0, stream, x, ln_g, ln_b, xnh, xnl);
    hipLaunchKernelGGL(wsplit_qkv, dim3(8, 24),   dim3(256), 0, stream, w_qkv, wqh, wql);
    hipLaunchKernelGGL(wsplit_out, dim3(8, 8),    dim3(256), 0, stream, w_out, wo);
    hipLaunchKernelGGL(nullkv2,    dim3(4),       dim3(256), 0, stream, nullkv, kh, kl, vT);
    hipLaunchKernelGGL(qkv_mfma,   dim3(32, 24),  dim3(256), 0, stream, xnh, xnl, wqh, wql, qh, ql, kh, kl, vT);
    hipLaunchKernelGGL(qk_mfma,    dim3(152, 8),  dim3(256), 0, stream, qh, ql, kh, kl, s);
    hipLaunchKernelGGL(cd_kernel,  dim3(4096),    dim3(64),  0, stream, s);
    hipLaunchKernelGGL(pv_mfma,    dim3(64, 8),   dim3(256), 0, stream, s, vT, ao);
    hipLaunchKernelGGL(out_mfma,   dim3(64, 8),   dim3(256), 0, stream, ao, wo, out);
}

// Round 9
// 170.426 us; speedup vs baseline: 6.7456x; 1.0604x over previous
//
#include <hip/hip_runtime.h>
#include <math.h>

#define NHEAD 8
#define SROW 1088          // s row stride (fp32)
#define PBF  2176          // bf16 slots per s row (aliased p storage)
#define VSTR 1056          // vT row length (bf16)
#define LOGK 2.0794415416798357f

typedef __bf16 bf16x8 __attribute__((ext_vector_type(8)));
typedef __bf16 bf16x4 __attribute__((ext_vector_type(4)));
typedef float  f32x4  __attribute__((ext_vector_type(4)));

__device__ __forceinline__ void split2(float v, __bf16& hi, __bf16& lo) {
    hi = (__bf16)v; lo = (__bf16)(v - (float)hi);
}

// ---------------- DPP wave reductions (64 lanes), result broadcast ----------------
__device__ __forceinline__ float dpp_sum64(float x) {
    int v;
    v = __builtin_amdgcn_update_dpp(0, __float_as_int(x), 0x111, 0xf, 0xf, true); x += __int_as_float(v);
    v = __builtin_amdgcn_update_dpp(0, __float_as_int(x), 0x112, 0xf, 0xf, true); x += __int_as_float(v);
    v = __builtin_amdgcn_update_dpp(0, __float_as_int(x), 0x114, 0xf, 0xf, true); x += __int_as_float(v);
    v = __builtin_amdgcn_update_dpp(0, __float_as_int(x), 0x118, 0xf, 0xf, true); x += __int_as_float(v);
    v = __builtin_amdgcn_update_dpp(0, __float_as_int(x), 0x142, 0xa, 0xf, true); x += __int_as_float(v);
    v = __builtin_amdgcn_update_dpp(0, __float_as_int(x), 0x143, 0xc, 0xf, true); x += __int_as_float(v);
    return __int_as_float(__builtin_amdgcn_readlane(__float_as_int(x), 63));
}
__device__ __forceinline__ float dpp_max64(float x) {
    int v;
    v = __builtin_amdgcn_update_dpp(__float_as_int(x), __float_as_int(x), 0x111, 0xf, 0xf, false); x = fmaxf(x, __int_as_float(v));
    v = __builtin_amdgcn_update_dpp(__float_as_int(x), __float_as_int(x), 0x112, 0xf, 0xf, false); x = fmaxf(x, __int_as_float(v));
    v = __builtin_amdgcn_update_dpp(__float_as_int(x), __float_as_int(x), 0x114, 0xf, 0xf, false); x = fmaxf(x, __int_as_float(v));
    v = __builtin_amdgcn_update_dpp(__float_as_int(x), __float_as_int(x), 0x118, 0xf, 0xf, false); x = fmaxf(x, __int_as_float(v));
    v = __builtin_amdgcn_update_dpp(__float_as_int(x), __float_as_int(x), 0x142, 0xa, 0xf, false); x = fmaxf(x, __int_as_float(v));
    v = __builtin_amdgcn_update_dpp(__float_as_int(x), __float_as_int(x), 0x143, 0xc, 0xf, false); x = fmaxf(x, __int_as_float(v));
    return __int_as_float(__builtin_amdgcn_readlane(__float_as_int(x), 63));
}

// ================== fused prep: ln (512 blk) + wsplit_qkv (192) + wsplit_out (64) + nullkv (4) ==================
__global__ __launch_bounds__(256) void prep_kernel(const float* __restrict__ x,
                                                   const float* __restrict__ g,
                                                   const float* __restrict__ bb,
                                                   const float* __restrict__ w_qkv,
                                                   const float* __restrict__ w_out,
                                                   const float* __restrict__ nkv,
                                                   __bf16* __restrict__ xnh,
                                                   __bf16* __restrict__ xnl,
                                                   __bf16* __restrict__ wqh,
                                                   __bf16* __restrict__ wql,
                                                   __bf16* __restrict__ wo,
                                                   __bf16* __restrict__ kh,
                                                   __bf16* __restrict__ kl,
                                                   __bf16* __restrict__ vT) {
    __shared__ float T[64][65];
    __shared__ float sm[2][4];
    int b = blockIdx.x, tid = threadIdx.x;

    if (b < 512) {
        // -------- LayerNorm, 2 rows per block --------
        int half = tid >> 7, t = tid & 127;
        int row = (b << 1) + half;
        float4 v = ((const float4*)(x + (size_t)row * 512))[t];
        float s  = v.x + v.y + v.z + v.w;
        float ss = fmaf(v.x, v.x, fmaf(v.y, v.y, fmaf(v.z, v.z, v.w * v.w)));
#pragma unroll
        for (int off = 32; off; off >>= 1) {
            s  += __shfl_down(s, off);
            ss += __shfl_down(ss, off);
        }
        int wih = (tid >> 6) & 1;   // wave within half
        if ((tid & 63) == 0) { sm[half][wih * 2] = s; sm[half][wih * 2 + 1] = ss; }
        __syncthreads();
        s = sm[half][0] + sm[half][2]; ss = sm[half][1] + sm[half][3];
        float mu   = s * (1.f / 512);
        float var  = ss * (1.f / 512) - mu * mu;
        float rstd = 1.f / sqrtf(var + 1e-5f);
        float4 gv = ((const float4*)g)[t];
        float4 bv = ((const float4*)bb)[t];
        float o[4];
        o[0] = (v.x - mu) * rstd * gv.x + bv.x;
        o[1] = (v.y - mu) * rstd * gv.y + bv.y;
        o[2] = (v.z - mu) * rstd * gv.z + bv.z;
        o[3] = (v.w - mu) * rstd * gv.w + bv.w;
        bf16x4 h4, l4;
#pragma unroll
        for (int e = 0; e < 4; ++e) { __bf16 hi, lo; split2(o[e], hi, lo); h4[e] = hi; l4[e] = lo; }
        *(bf16x4*)(xnh + (size_t)row * 512 + t * 4) = h4;
        *(bf16x4*)(xnl + (size_t)row * 512 + t * 4) = l4;
    } else if (b < 704) {
        // -------- w_qkv [512k][1536n] -> split bf16 [n][k] --------
        int b2 = b - 512;
        int k0 = (b2 & 7) * 64, n0 = (b2 >> 3) * 64;
        int r = tid >> 2, c0 = (tid & 3) << 4;
#pragma unroll
        for (int u = 0; u < 4; ++u) {
            float4 w = *(const float4*)(w_qkv + (size_t)(k0 + r) * 1536 + n0 + c0 + 4 * u);
            T[r][c0 + 4 * u + 0] = w.x; T[r][c0 + 4 * u + 1] = w.y;
            T[r][c0 + 4 * u + 2] = w.z; T[r][c0 + 4 * u + 3] = w.w;
        }
        __syncthreads();
        int nr = tid >> 2, kc0 = (tid & 3) << 4;
#pragma unroll
        for (int u = 0; u < 4; ++u) {
            bf16x4 h4, l4;
#pragma unroll
            for (int e = 0; e < 4; ++e) {
                __bf16 hi, lo; split2(T[kc0 + 4 * u + e][nr], hi, lo);
                h4[e] = hi; l4[e] = lo;
            }
            *(bf16x4*)(wqh + (size_t)(n0 + nr) * 512 + k0 + kc0 + 4 * u) = h4;
            *(bf16x4*)(wql + (size_t)(n0 + nr) * 512 + k0 + kc0 + 4 * u) = l4;
        }
    } else if (b < 768) {
        // -------- w_out [512][512] -> bf16 [n][k] --------
        int b2 = b - 704;
        int k0 = (b2 & 7) * 64, n0 = (b2 >> 3) * 64;
        int r = tid >> 2, c0 = (tid & 3) << 4;
#pragma unroll
        for (int u = 0; u < 4; ++u) {
            float4 w = *(const float4*)(w_out + (size_t)(k0 + r) * 512 + n0 + c0 + 4 * u);
            T[r][c0 + 4 * u + 0] = w.x; T[r][c0 + 4 * u + 1] = w.y;
            T[r][c0 + 4 * u + 2] = w.z; T[r][c0 + 4 * u + 3] = w.w;
        }
        __syncthreads();
        int nr = tid >> 2, kc0 = (tid & 3) << 4;
#pragma unroll
        for (int u = 0; u < 4; ++u) {
            bf16x4 h4;
#pragma unroll
            for (int e = 0; e < 4; ++e) h4[e] = (__bf16)T[kc0 + 4 * u + e][nr];
            *(bf16x4*)(wo + (size_t)(n0 + nr) * 512 + k0 + kc0 + 4 * u) = h4;
        }
    } else {
        // -------- null kv + vT tail zero --------
        int t2 = (b - 768) * 256 + tid;   // 0..1023
        int d = t2 & 63, p = (t2 >> 6) & 1, h = t2 >> 7;
        float kvf = nkv[((0 * NHEAD + h) * 2 + p) * 64 + d];
        __bf16 hi, lo; split2(kvf, hi, lo);
        kh[((size_t)h * SROW + p) * 64 + d] = hi;
        kl[((size_t)h * SROW + p) * 64 + d] = lo;
        float vf = nkv[((NHEAD + h) * 2 + p) * 64 + d];
        vT[((size_t)(h * 64) + d) * VSTR + p] = (__bf16)vf;
        int base = t2 * 15;
#pragma unroll
        for (int e = 0; e < 15; ++e) {
            int z = base + e;
            int jj = 1026 + (z % 30);
            int hd = z / 30;
            vT[(size_t)hd * VSTR + jj] = (__bf16)0.f;
        }
    }
}

// ============ QKV GEMM: LDS-free 3-pass MFMA ============
// grid (32, 24): tile 32m x 64n, 4 waves (2 m-stripes x 2 n-halves)
__global__ __launch_bounds__(256, 2) void qkv_mfma(const __bf16* __restrict__ xh,
                                                   const __bf16* __restrict__ xl,
                                                   const __bf16* __restrict__ bh,
                                                   const __bf16* __restrict__ bl,
                                                   __bf16* __restrict__ qh,
                                                   __bf16* __restrict__ ql,
                                                   __bf16* __restrict__ kh,
                                                   __bf16* __restrict__ kl,
                                                   __bf16* __restrict__ vT) {
    int tid = threadIdx.x, l = tid & 63, w = tid >> 6;
    int m0 = blockIdx.x * 32, n0 = blockIdx.y * 64;
    int ms = (w & 1) << 4, nh2 = (w >> 1) << 5;
    int arow = m0 + ms + (l & 15);
    f32x4 acc[2] = {};
    for (int ks = 0; ks < 16; ++ks) {
        int koff = ((l >> 4) << 3) + (ks << 5);
        bf16x8 ah = *(const bf16x8*)(xh + (size_t)arow * 512 + koff);
        bf16x8 al = *(const bf16x8*)(xl + (size_t)arow * 512 + koff);
#pragma unroll
        for (int ct = 0; ct < 2; ++ct) {
            int ncol = n0 + nh2 + (ct << 4) + (l & 15);
            bf16x8 bhv = *(const bf16x8*)(bh + (size_t)ncol * 512 + koff);
            bf16x8 blv = *(const bf16x8*)(bl + (size_t)ncol * 512 + koff);
            acc[ct] = __builtin_amdgcn_mfma_f32_16x16x32_bf16(ah, bhv, acc[ct], 0, 0, 0);
            acc[ct] = __builtin_amdgcn_mfma_f32_16x16x32_bf16(al, bhv, acc[ct], 0, 0, 0);
            acc[ct] = __builtin_amdgcn_mfma_f32_16x16x32_bf16(ah, blv, acc[ct], 0, 0, 0);
        }
    }
#pragma unroll
    for (int ct = 0; ct < 2; ++ct) {
        int c = n0 + nh2 + (ct << 4) + (l & 15);
#pragma unroll
        for (int r = 0; r < 4; ++r) {
            int m = m0 + ms + ((l >> 4) << 2) + r;
            float val = acc[ct][r];
            if (c < 512) {
                int h = c >> 6, d = c & 63;
                __bf16 hi, lo; split2(val * 1.25f, hi, lo);   // 0.125 scale * 10 (1/eps)
                qh[(((size_t)(h << 10)) + m) * 64 + d] = hi;
                ql[(((size_t)(h << 10)) + m) * 64 + d] = lo;
            } else if (c < 1024) {
                int c2 = c - 512, h = c2 >> 6, d = c2 & 63;
                __bf16 hi, lo; split2(val, hi, lo);
                kh[((size_t)h * SROW + 2 + m) * 64 + d] = hi;
                kl[((size_t)h * SROW + 2 + m) * 64 + d] = lo;
            } else {
                int c2 = c - 1024, h = c2 >> 6, d = c2 & 63;
                vT[((size_t)(h * 64) + d) * VSTR + 2 + m] = (__bf16)val;
            }
        }
    }
}

// ============ QK^T: LDS-free 3-pass MFMA, causal tiles only ============
__global__ __launch_bounds__(256, 2) void qk_mfma(const __bf16* __restrict__ qh,
                                                  const __bf16* __restrict__ ql,
                                                  const __bf16* __restrict__ kh,
                                                  const __bf16* __restrict__ kl,
                                                  float* __restrict__ s) {
    int b = blockIdx.x, h = blockIdx.y;
    int ti = (int)((-3.0f + sqrtf(9.0f + 8.0f * (float)b)) * 0.5f);
    while ((ti + 1) * (ti + 4) / 2 <= b) ++ti;
    while (ti * (ti + 3) / 2 > b) --ti;
    int tj = b - ti * (ti + 3) / 2;
    int i0 = ti << 6, j0 = tj << 6;

    int tid = threadIdx.x, l = tid & 63, w = tid >> 6;
    int arow = i0 + (w << 4) + (l & 15);
    const __bf16* qhb = qh + ((size_t)(h << 10) + arow) * 64;
    const __bf16* qlb = ql + ((size_t)(h << 10) + arow) * 64;
    f32x4 acc[4] = {};
#pragma unroll
    for (int ks = 0; ks < 2; ++ks) {
        int koff = ((l >> 4) << 3) + (ks << 5);
        bf16x8 ah = *(const bf16x8*)(qhb + koff);
        bf16x8 al = *(const bf16x8*)(qlb + koff);
#pragma unroll
        for (int ct = 0; ct < 4; ++ct) {
            int j = j0 + (ct << 4) + (l & 15);
            bf16x8 bhv = *(const bf16x8*)(kh + ((size_t)h * SROW + j) * 64 + koff);
            bf16x8 blv = *(const bf16x8*)(kl + ((size_t)h * SROW + j) * 64 + koff);
            acc[ct] = __builtin_amdgcn_mfma_f32_16x16x32_bf16(ah, bhv, acc[ct], 0, 0, 0);
            acc[ct] = __builtin_amdgcn_mfma_f32_16x16x32_bf16(al, bhv, acc[ct], 0, 0, 0);
            acc[ct] = __builtin_amdgcn_mfma_f32_16x16x32_bf16(ah, blv, acc[ct], 0, 0, 0);
        }
    }
#pragma unroll
    for (int ct = 0; ct < 4; ++ct) {
        int j = j0 + (ct << 4) + (l & 15);
#pragma unroll
        for (int r = 0; r < 4; ++r) {
            int i = i0 + (w << 4) + ((l >> 4) << 2) + r;
            s[((size_t)(h << 10) + i) * SROW + j] = acc[ct][r];
        }
    }
}

// ---------------- CD: 128-thr blocks (2 pairs), 8 waves/SIMD, no E2 table ----------------
__global__ __launch_bounds__(128, 8) void cd_kernel(float* __restrict__ s) {
    int lane = threadIdx.x & 63;
    int p = (blockIdx.x << 1) + (threadIdx.x >> 6);
    int h = p >> 9, ip = p & 511;
    int iA = 1023 - ip, iB = ip;
    int nvA = iA + 3, nvB = iB + 3;
    float* rA = s + ((size_t)(h << 10) + iA) * SROW;
    float* rB = s + ((size_t)(h << 10) + iB) * SROW;
    int jb = lane << 2;

    float4 EA[5], EB[3];
#pragma unroll
    for (int t = 0; t < 5; ++t) {
        if (jb + (t << 8) < SROW) EA[t] = *(const float4*)(rA + jb + (t << 8));
        else { EA[t].x = EA[t].y = EA[t].z = EA[t].w = -INFINITY; }
    }
#pragma unroll
    for (int t = 0; t < 3; ++t) EB[t] = *(const float4*)(rB + jb + (t << 8));

    // mask + row max (s already x10)
    float mA = -INFINITY, mB = -INFINITY;
#pragma unroll
    for (int t = 0; t < 5; ++t) {
        float* sp = (float*)&EA[t];
#pragma unroll
        for (int c = 0; c < 4; ++c) {
            int j = jb + c + (t << 8);
            float v = (j < nvA) ? sp[c] : -INFINITY;
            sp[c] = v; mA = fmaxf(mA, v);
        }
    }
#pragma unroll
    for (int t = 0; t < 3; ++t) {
        float* sp = (float*)&EB[t];
#pragma unroll
        for (int c = 0; c < 4; ++c) {
            int j = jb + c + (t << 8);
            float v = (j < nvB) ? sp[c] : -INFINITY;
            sp[c] = v; mB = fmaxf(mB, v);
        }
    }
    mA = dpp_max64(mA); mB = dpp_max64(mB);

    // E tables in-place (masked -> exp(-inf)=0)
#pragma unroll
    for (int t = 0; t < 5; ++t) {
        float* sp = (float*)&EA[t];
#pragma unroll
        for (int c = 0; c < 4; ++c) sp[c] = __expf(sp[c] - mA);
    }
#pragma unroll
    for (int t = 0; t < 3; ++t) {
        float* sp = (float*)&EB[t];
#pragma unroll
        for (int c = 0; c < 4; ++c) sp[c] = __expf(sp[c] - mB);
    }

    float gA = LOGK - __logf((float)nvA) + mA;
    float gB = LOGK - __logf((float)nvB) + mB;
    bool dA = false, dB = false;
#pragma unroll 1
    for (int it = 1; it < 50; ++it) {
        if (!dA) {
            float eg = __expf(fminf(gA, 80.f));
            float a0 = 0.f, a1 = 0.f, a2 = 0.f, a3 = 0.f;
#pragma unroll
            for (int t = 0; t < 5; ++t) {
                float* ep = (float*)&EA[t];
                a0 += ep[0] * fminf(1.f, ep[0] * eg);
                a1 += ep[1] * fminf(1.f, ep[1] * eg);
                a2 += ep[2] * fminf(1.f, ep[2] * eg);
                a3 += ep[3] * fminf(1.f, ep[3] * eg);
            }
            float sum = dpp_sum64((a0 + a1) + (a2 + a3));
            float g2 = LOGK - __logf(sum);
            dA = (__float_as_int(g2) == __float_as_int(gA));
            gA = g2;
        }
        if (!dB) {
            float eg = __expf(fminf(gB, 80.f));
            float b0 = 0.f, b1 = 0.f, b2 = 0.f, b3 = 0.f;
#pragma unroll
            for (int t = 0; t < 3; ++t) {
                float* ep = (float*)&EB[t];
                b0 += ep[0] * fminf(1.f, ep[0] * eg);
                b1 += ep[1] * fminf(1.f, ep[1] * eg);
                b2 += ep[2] * fminf(1.f, ep[2] * eg);
                b3 += ep[3] * fminf(1.f, ep[3] * eg);
            }
            float sum = dpp_sum64((b0 + b1) + (b2 + b3));
            float g2 = LOGK - __logf(sum);
            dB = (__float_as_int(g2) == __float_as_int(gB));
            gB = g2;
        }
        if (dA && dB) break;
    }

    // final p -> bf16, written over the s rows (fully read above)
    float egA = __expf(fminf(gA, 80.f));
    float egB = __expf(fminf(gB, 80.f));
    __bf16* pA = (__bf16*)rA;
    __bf16* pB = (__bf16*)rB;
#pragma unroll
    for (int t = 0; t < 5; ++t) {
        if (jb + (t << 8) < SROW) {
            bf16x4 pv;
            float* ep = (float*)&EA[t];
#pragma unroll
            for (int c = 0; c < 4; ++c) {
                float wv = ep[c] * egA;
                pv[c] = (__bf16)(wv * fminf(1.f, wv));
            }
            *(bf16x4*)(pA + jb + (t << 8)) = pv;
        }
    }
#pragma unroll
    for (int t = 0; t < 3; ++t) {
        bf16x4 pv;
        float* ep = (float*)&EB[t];
#pragma unroll
        for (int c = 0; c < 4; ++c) {
            float wv = ep[c] * egB;
            pv[c] = (__bf16)(wv * fminf(1.f, wv));
        }
        *(bf16x4*)(pB + jb + (t << 8)) = pv;
    }
    bf16x4 z4 = {};
#pragma unroll
    for (int t = 3; t < 5; ++t) {
        if (jb + (t << 8) < SROW) *(bf16x4*)(pB + jb + (t << 8)) = z4;
    }
}

// ============ PV: LDS-free bf16 MFMA. grid (64, 8): tile 16i x 64d ============
__global__ __launch_bounds__(256, 2) void pv_mfma(const float* __restrict__ s,
                                                  const __bf16* __restrict__ vT,
                                                  __bf16* __restrict__ ao) {
    int i0 = blockIdx.x << 4, h = blockIdx.y;
    int tid = threadIdx.x, l = tid & 63, w = tid >> 6;
    const __bf16* pbase = (const __bf16*)s;
    int arow = i0 + (l & 15);
    int dcol = (w << 4) + (l & 15);
    const __bf16* pr = pbase + ((size_t)(h << 10) + arow) * PBF;
    const __bf16* vr = vT + ((size_t)(h << 6) + dcol) * VSTR;
    f32x4 acc0 = {}, acc1 = {};
    int kb = (l >> 4) << 3;
#pragma unroll 4
    for (int ks = 0; ks < 32; ks += 2) {
        bf16x8 a0 = *(const bf16x8*)(pr + kb + (ks << 5));
        bf16x8 b0 = *(const bf16x8*)(vr + kb + (ks << 5));
        bf16x8 a1 = *(const bf16x8*)(pr + kb + ((ks + 1) << 5));
        bf16x8 b1 = *(const bf16x8*)(vr + kb + ((ks + 1) << 5));
        acc0 = __builtin_amdgcn_mfma_f32_16x16x32_bf16(a0, b0, acc0, 0, 0, 0);
        acc1 = __builtin_amdgcn_mfma_f32_16x16x32_bf16(a1, b1, acc1, 0, 0, 0);
    }
    {
        bf16x8 a0 = *(const bf16x8*)(pr + kb + (32 << 5));
        bf16x8 b0 = *(const bf16x8*)(vr + kb + (32 << 5));
        acc0 = __builtin_amdgcn_mfma_f32_16x16x32_bf16(a0, b0, acc0, 0, 0, 0);
    }
#pragma unroll
    for (int r = 0; r < 4; ++r) {
        int i = i0 + ((l >> 4) << 2) + r;
        ao[(size_t)i * 512 + (h << 6) + dcol] = (__bf16)(acc0[r] + acc1[r]);
    }
}

// ============ OUT: LDS-free bf16 MFMA. grid (64, 8): tile 16m x 64n ============
__global__ __launch_bounds__(256, 2) void out_mfma(const __bf16* __restrict__ ao,
                                                   const __bf16* __restrict__ wo,
                                                   float* __restrict__ out) {
    int m0 = blockIdx.x << 4, bn = blockIdx.y;
    int tid = threadIdx.x, l = tid & 63, w = tid >> 6;
    int arow = m0 + (l & 15);
    int ncol = (bn << 6) + (w << 4) + (l & 15);
    const __bf16* ar = ao + (size_t)arow * 512;
    const __bf16* br = wo + (size_t)ncol * 512;
    f32x4 acc0 = {}, acc1 = {};
    int kb = (l >> 4) << 3;
#pragma unroll 4
    for (int ks = 0; ks < 16; ks += 2) {
        bf16x8 a0 = *(const bf16x8*)(ar + kb + (ks << 5));
        bf16x8 b0 = *(const bf16x8*)(br + kb + (ks << 5));
        bf16x8 a1 = *(const bf16x8*)(ar + kb + ((ks + 1) << 5));
        bf16x8 b1 = *(const bf16x8*)(br + kb + ((ks + 1) << 5));
        acc0 = __builtin_amdgcn_mfma_f32_16x16x32_bf16(a0, b0, acc0, 0, 0, 0);
        acc1 = __builtin_amdgcn_mfma_f32_16x16x32_bf16(a1, b1, acc1, 0, 0, 0);
    }
#pragma unroll
    for (int r = 0; r < 4; ++r) {
        int m = m0 + ((l >> 4) << 2) + r;
        out[(size_t)m * 512 + ncol] = acc0[r] + acc1[r];
    }
}

extern "C" void kernel_launch(void* const* d_in, const int* in_sizes, int n_in,
                              void* d_out, int out_size, void* d_ws, size_t ws_size,
                              hipStream_t stream) {
    const float* x      = (const float*)d_in[0];
    const float* w_qkv  = (const float*)d_in[1];
    const float* w_out  = (const float*)d_in[2];
    const float* nullkv = (const float*)d_in[3];
    const float* ln_g   = (const float*)d_in[4];
    const float* ln_b   = (const float*)d_in[5];
    float* ws = (float*)d_ws;
    float* out = (float*)d_out;

    float* base = ws;
    __bf16* xnh = (__bf16*)(base);              base += 262144;   // 1024*512 bf16
    __bf16* xnl = (__bf16*)(base);              base += 262144;
    __bf16* wqh = (__bf16*)(base);              base += 393216;   // 1536*512 bf16
    __bf16* wql = (__bf16*)(base);              base += 393216;
    __bf16* qh  = (__bf16*)(base);              base += 262144;   // 8*1024*64
    __bf16* ql  = (__bf16*)(base);              base += 262144;
    __bf16* kh  = (__bf16*)(base);              base += 278528;   // 8*1088*64
    __bf16* kl  = (__bf16*)(base);              base += 278528;
    __bf16* vT  = (__bf16*)(base);              base += 270336;   // 8*64*1056
    __bf16* wo  = (__bf16*)(base);              base += 131072;   // 512*512
    __bf16* ao  = (__bf16*)(base);              base += 262144;   // 1024*512
    float*  s   = base;                                           // 8*1024*1088 fp32 (p aliased)

    hipLaunchKernelGGL(prep_kernel, dim3(772),    dim3(256), 0, stream,
                       x, ln_g, ln_b, w_qkv, w_out, nullkv,
                       xnh, xnl, wqh, wql, wo, kh, kl, vT);
    hipLaunchKernelGGL(qkv_mfma,   dim3(32, 24),  dim3(256), 0, stream, xnh, xnl, wqh, wql, qh, ql, kh, kl, vT);
    hipLaunchKernelGGL(qk_mfma,    dim3(152, 8),  dim3(256), 0, stream, qh, ql, kh, kl, s);
    hipLaunchKernelGGL(cd_kernel,  dim3(2048),    dim3(128), 0, stream, s);
    hipLaunchKernelGGL(pv_mfma,    dim3(64, 8),   dim3(256), 0, stream, s, vT, ao);
    hipLaunchKernelGGL(out_mfma,   dim3(64, 8),   dim3(256), 0, stream, ao, wo, out);
}